// Round 7
// baseline (518.233 us; speedup 1.0000x reference)
//
#include <hip/hip_runtime.h>
#include <math.h>

#define TOK 2309
#define CH 1024
#define NH 16
#define HD 64
#define NREG 5
#define NTOK (TOK - NREG)    // 2304
#define NPADQ 2432           // 38*64 (query/M padding)
#define NPAD2 2560           // 40*64 (key padding)
#define HTILES 20            // K-tiles per half
#define NQROW 2368           // 37*64 rows in attention output partials
#define QSCL 0.1803368801f   // 0.125 * log2(e)

typedef unsigned short ushort_t;
typedef __attribute__((ext_vector_type(8))) short s8frag;
typedef __attribute__((ext_vector_type(4))) float f4frag;

__device__ __forceinline__ float wredsum(float v){
  #pragma unroll
  for (int o = 32; o > 0; o >>= 1) v += __shfl_xor(v, o, 64);
  return v;
}

__device__ __forceinline__ unsigned short f2bf(float x){
  union { float f; unsigned u; } v; v.f = x;
  unsigned r = v.u + 0x7FFF + ((v.u >> 16) & 1);
  return (unsigned short)(r >> 16);
}
__device__ __forceinline__ float bf2f(unsigned short u){
  union { unsigned u32; float f; } v; v.u32 = ((unsigned)u) << 16;
  return v.f;
}
// pack two floats to bf16x2 (round-half-up on magnitude) in ~3 ops
__device__ __forceinline__ unsigned pack_bf16(float lo, float hi){
  union { float f; unsigned u; } a, b;
  a.f = lo; b.f = hi;
  return __builtin_amdgcn_perm(b.u + 0x8000u, a.u + 0x8000u, 0x07060302u);
}
// async global->LDS 16B per lane; l must be wave-uniform base (HW adds lane*16)
__device__ __forceinline__ void cp16(const ushort_t* g, ushort_t* l){
  __builtin_amdgcn_global_load_lds(
      (const __attribute__((address_space(1))) unsigned int*)g,
      (__attribute__((address_space(3))) unsigned int*)l, 16, 0, 0);
}

// ---------------- split X into hi/lo bf16 (rows padded to NPADQ with zeros) --------
__global__ __launch_bounds__(256) void split_x_kernel(
    const float* __restrict__ X, ushort_t* __restrict__ Xhi, ushort_t* __restrict__ Xlo)
{
  int row = blockIdx.x;
  int c4 = threadIdx.x * 4;
  ushort4 h4 = {0,0,0,0}, l4 = {0,0,0,0};
  if (row < TOK) {
    float4 v = *(const float4*)&X[(size_t)row*CH + c4];
    float vv[4] = {v.x, v.y, v.z, v.w};
    ushort_t hs[4], ls[4];
    #pragma unroll
    for (int i = 0; i < 4; i++) {
      hs[i] = f2bf(vv[i]);
      ls[i] = f2bf(vv[i] - bf2f(hs[i]));
    }
    h4.x=hs[0]; h4.y=hs[1]; h4.z=hs[2]; h4.w=hs[3];
    l4.x=ls[0]; l4.y=ls[1]; l4.z=ls[2]; l4.w=ls[3];
  }
  *(ushort4*)&Xhi[(size_t)row*CH + c4] = h4;
  *(ushort4*)&Xlo[(size_t)row*CH + c4] = l4;
}

// ---------------- transpose+split W: W(1024 x N) -> WT(N x 1024) bf16 (+lo) --------
__global__ __launch_bounds__(256) void pack_w_kernel(
    const float* __restrict__ W, const int N,
    ushort_t* __restrict__ WT, ushort_t* __restrict__ WloT, const int loN)
{
  __shared__ float T[64][68];
  const int tid = threadIdx.x;
  const int n0 = blockIdx.x * 64;
  const int k0 = blockIdx.y * 64;
  const int lr = tid >> 4;
  const int lc = (tid & 15) * 4;
  #pragma unroll
  for (int s = 0; s < 4; s++) {
    float4 v = *(const float4*)&W[(size_t)(k0 + lr + s*16) * N + n0 + lc];
    *(float4*)&T[lr + s*16][lc] = v;
  }
  __syncthreads();
  const int nl = tid >> 2;
  const int kc = (tid & 3) * 16;
  const bool dolo = (WloT != nullptr) && (n0 < loN);
  ushort_t* dh = WT + (size_t)(n0 + nl) * CH + k0 + kc;
  ushort_t* dl = WloT + (size_t)(n0 + nl) * CH + k0 + kc;
  #pragma unroll
  for (int g = 0; g < 4; g++) {
    float a = T[kc+g*4+0][nl], b = T[kc+g*4+1][nl];
    float c = T[kc+g*4+2][nl], d = T[kc+g*4+3][nl];
    ushort4 oh;
    oh.x=f2bf(a); oh.y=f2bf(b); oh.z=f2bf(c); oh.w=f2bf(d);
    *(ushort4*)&dh[g*4] = oh;
    if (dolo) {
      ushort4 ol;
      ol.x=f2bf(a-bf2f(oh.x)); ol.y=f2bf(b-bf2f(oh.y));
      ol.z=f2bf(c-bf2f(oh.z)); ol.w=f2bf(d-bf2f(oh.w));
      *(ushort4*)&dl[g*4] = ol;
    }
  }
}

// ---------------- QKV GEMM via MFMA, 64-row M tiles (high TLP) ----------------------
__global__ __launch_bounds__(256) void gemm_qkv_mfma(
    const ushort_t* __restrict__ Xhi, const ushort_t* __restrict__ Xlo,
    const ushort_t* __restrict__ WhiT, const ushort_t* __restrict__ WloT,
    float* __restrict__ Qf, ushort_t* __restrict__ Qbf,
    ushort_t* __restrict__ Kbf, ushort_t* __restrict__ VTbf)
{
  const int tid = threadIdx.x;
  const int w = tid >> 6, lane = tid & 63;
  const int quad = lane >> 4, c16 = lane & 15;
  const int n0 = blockIdx.x * 64;
  const int m0 = blockIdx.y * 64;
  const int three = n0 >> 10;
  const int h = (n0 >> 6) & 15;
  const bool isQ = (three == 0);
  const ushort_t* xh0 = Xhi + (size_t)(m0 + w*16 + c16)*CH + quad*8;
  const ushort_t* xl0 = Xlo + (size_t)(m0 + w*16 + c16)*CH + quad*8;
  const ushort_t* wb0 = WhiT + (size_t)(n0 + c16)*CH + quad*8;
  const ushort_t* wl0 = WloT + (size_t)(n0 + c16)*CH + quad*8;
  f4frag acc[4];
  #pragma unroll
  for (int nb = 0; nb < 4; nb++) acc[nb] = (f4frag){0.f,0.f,0.f,0.f};

  #pragma unroll 2
  for (int k0 = 0; k0 < CH; k0 += 32) {
    s8frag ah = *(const s8frag*)(xh0 + k0);
    s8frag wh[4];
    #pragma unroll
    for (int nb = 0; nb < 4; nb++) wh[nb] = *(const s8frag*)(wb0 + (size_t)nb*16*CH + k0);
    if (isQ) {
      s8frag al = *(const s8frag*)(xl0 + k0);
      s8frag wl[4];
      #pragma unroll
      for (int nb = 0; nb < 4; nb++) wl[nb] = *(const s8frag*)(wl0 + (size_t)nb*16*CH + k0);
      #pragma unroll
      for (int nb = 0; nb < 4; nb++) {
        acc[nb] = __builtin_amdgcn_mfma_f32_16x16x32_bf16(ah, wh[nb], acc[nb], 0, 0, 0);
        acc[nb] = __builtin_amdgcn_mfma_f32_16x16x32_bf16(ah, wl[nb], acc[nb], 0, 0, 0);
        acc[nb] = __builtin_amdgcn_mfma_f32_16x16x32_bf16(al, wh[nb], acc[nb], 0, 0, 0);
      }
    } else {
      #pragma unroll
      for (int nb = 0; nb < 4; nb++)
        acc[nb] = __builtin_amdgcn_mfma_f32_16x16x32_bf16(ah, wh[nb], acc[nb], 0, 0, 0);
    }
  }

  const int orow = m0 + w*16 + quad*4;
  if (three == 0) {
    float* qf = Qf + (size_t)h*TOK*HD;
    ushort_t* qb = Qbf + (size_t)h*NPADQ*HD;
    #pragma unroll
    for (int nb = 0; nb < 4; nb++) {
      int d = nb*16 + c16;
      #pragma unroll
      for (int r = 0; r < 4; r++) {
        int row = orow + r;
        float v = (row < TOK) ? acc[nb][r] : 0.f;
        if (row < TOK) qf[(size_t)row*HD + d] = v;
        qb[(size_t)row*HD + d] = f2bf(v * QSCL);
      }
    }
  } else if (three == 1) {
    ushort_t* kb = Kbf + (size_t)h*NPAD2*HD;
    #pragma unroll
    for (int nb = 0; nb < 4; nb++) {
      int d = nb*16 + c16;
      #pragma unroll
      for (int r = 0; r < 4; r++) {
        int row = orow + r;
        float v = (row < TOK) ? acc[nb][r] : 0.f;
        kb[(size_t)row*HD + d] = f2bf(v);
      }
    }
  } else {
    ushort_t* vt = VTbf + (size_t)h*HD*NPAD2;
    #pragma unroll
    for (int nb = 0; nb < 4; nb++) {
      int d = nb*16 + c16;
      ushort4 o;
      o.x = f2bf((orow+0 < TOK) ? acc[nb][0] : 0.f);
      o.y = f2bf((orow+1 < TOK) ? acc[nb][1] : 0.f);
      o.z = f2bf((orow+2 < TOK) ? acc[nb][2] : 0.f);
      o.w = f2bf((orow+3 < TOK) ? acc[nb][3] : 0.f);
      *(ushort4*)&vt[(size_t)d*NPAD2 + orow] = o;
    }
  }
}

// ---------------- sim kernel (fp32 Q) ----------------------------------------------
__global__ __launch_bounds__(256) void sim_kernel(
    const float* __restrict__ Q, const float* __restrict__ G, float* __restrict__ sim)
{
  const int tid = threadIdx.x;
  const int w = tid >> 6, lane = tid & 63;
  float qgn[NH];
  #pragma unroll
  for (int h = 0; h < NH; h++) {
    float g = G[h*HD + lane];
    float n2 = wredsum(g*g);
    qgn[h] = g / sqrtf(n2);
  }
  int it = blockIdx.x * 4 + w;
  if (it >= NTOK) return;
  int i = NREG + it;
  float acc = 0.f;
  #pragma unroll
  for (int h = 0; h < NH; h++) {
    float qv = Q[((size_t)h*TOK + i)*HD + lane];
    float dot = wredsum(qv * qgn[h]);
    float n2  = wredsum(qv * qv);
    acc += dot / sqrtf(n2);
  }
  if (lane == 0) sim[it] = acc * (1.0f/16.0f);
}

// ---------------- mask kernel ------------------------------------------------------
__global__ __launch_bounds__(256) void mask_kernel(
    const float* __restrict__ sim, int* __restrict__ cls,
    float* __restrict__ WP, float* __restrict__ WN)
{
  __shared__ float smn[256], smx[256];
  const int tid = threadIdx.x;
  float mn = 1e30f, mx = -1e30f;
  for (int i = tid; i < NTOK; i += 256) { float s = sim[i]; mn = fminf(mn, s); mx = fmaxf(mx, s); }
  smn[tid] = mn; smx[tid] = mx;
  __syncthreads();
  for (int off = 128; off > 0; off >>= 1) {
    if (tid < off) { smn[tid] = fminf(smn[tid], smn[tid+off]); smx[tid] = fmaxf(smx[tid], smx[tid+off]); }
    __syncthreads();
  }
  mn = smn[0]; mx = smx[0];
  float inv = 1.0f / (mx - mn);
  for (int j = tid; j < NPAD2; j += 256) {
    float wp = 0.f, wn = 0.f; int c = 0;
    if (j < NREG) { wp = 1.f; wn = 1.f; c = 2; }
    else if (j < TOK) {
      bool pos = ((sim[j-NREG] - mn) * inv) > 0.9f;
      c = pos ? 1 : 0;
      wp = pos ? 1.f : 0.f;
      wn = pos ? 0.f : 1.f;
    }
    WP[j] = wp; WN[j] = wn;
    if (j < TOK) cls[j] = c;
  }
}

// ---------------- MFMA flash attention, LDS-staged, split-K x2 across blocks --------
// block = (64 q, head, half); partial O (bf16, unnormalized) + partial l (fp32)
// are exactly additive (no running max anywhere).
__global__ __launch_bounds__(256) void attn_kernel(
    const ushort_t* __restrict__ Qbf, const ushort_t* __restrict__ Kbf,
    const ushort_t* __restrict__ VTbf,
    const float* __restrict__ WP, const float* __restrict__ WN,
    ushort_t* __restrict__ POp, ushort_t* __restrict__ POn,
    float* __restrict__ Lp, float* __restrict__ Ln)
{
  __shared__ ushort_t Kst[2*4096];   // 16 KB double-buffered K tile
  __shared__ ushort_t Vst[2*4096];   // 16 KB double-buffered V^T tile
  __shared__ union { ushort_t P[4][2][16][72]; float S[4][16][72]; } sm; // 18.4 KB
  const int tid = threadIdx.x;
  const int w = tid >> 6, lane = tid & 63;
  const int quad = lane >> 4, c16 = lane & 15;
  const int h = blockIdx.y;
  const int half = blockIdx.z;
  const int q0 = blockIdx.x * 64;
  const ushort_t* Qh  = Qbf  + (size_t)h * NPADQ * HD;
  const ushort_t* Kh  = Kbf  + (size_t)h * NPAD2 * HD + (size_t)half * HTILES * 64 * HD;
  const ushort_t* VTh = VTbf + (size_t)h * HD * NPAD2;

  s8frag qf0 = *(const s8frag*)(Qh + (size_t)(q0 + w*16 + c16)*HD + quad*8);
  s8frag qf1 = *(const s8frag*)(Qh + (size_t)(q0 + w*16 + c16)*HD + 32 + quad*8);

  // staging: granule gl of row stored at slot gl ^ (row&7)
  const int r1 = tid >> 3,         s1 = (tid & 7) ^ (r1 & 7);
  const int r2 = (tid + 256) >> 3, s2 = (tid & 7) ^ (r2 & 7);
  const ushort_t* gk1 = Kh + r1*HD + s1*8;
  const ushort_t* gk2 = Kh + r2*HD + s2*8;
  const ushort_t* gv1 = VTh + (size_t)r1*NPAD2 + half*(HTILES*64) + s1*8;
  const ushort_t* gv2 = VTh + (size_t)r2*NPAD2 + half*(HTILES*64) + s2*8;
  ushort_t* lk = &Kst[(tid & 192) * 8];   // wave-uniform
  ushort_t* lv = &Vst[(tid & 192) * 8];

  cp16(gk1, lk);        cp16(gk2, lk + 2048);
  cp16(gv1, lv);        cp16(gv2, lv + 2048);

  f4frag op[4], on[4];
  #pragma unroll
  for (int nb = 0; nb < 4; nb++) { op[nb] = (f4frag){0.f,0.f,0.f,0.f}; on[nb] = (f4frag){0.f,0.f,0.f,0.f}; }
  float lp = 0.f, ln = 0.f;
  const int sA = quad ^ (c16 & 7);

  int pb = 0;
  for (int t = 0; t < HTILES; t++) {
    __syncthreads();
    if (t < HTILES-1) {
      const int tn = t + 1;
      ushort_t* dk = lk + (pb^1)*4096;
      ushort_t* dv = lv + (pb^1)*4096;
      cp16(gk1 + tn*4096, dk);       cp16(gk2 + tn*4096, dk + 2048);
      cp16(gv1 + tn*64,   dv);       cp16(gv2 + tn*64,   dv + 2048);
    }
    const int j0 = half*(HTILES*64) + t*64;
    const int pbo = pb*4096;
    // ---- QK ----
    f4frag st[4];
    #pragma unroll
    for (int b = 0; b < 4; b++) {
      const int ro = pbo + (b*16 + c16)*64;
      s8frag kf0 = *(const s8frag*)&Kst[ro + sA*8];
      s8frag kf1 = *(const s8frag*)&Kst[ro + (sA^4)*8];
      f4frag z = (f4frag){0.f,0.f,0.f,0.f};
      z = __builtin_amdgcn_mfma_f32_16x16x32_bf16(kf0, qf0, z, 0, 0, 0);
      st[b] = __builtin_amdgcn_mfma_f32_16x16x32_bf16(kf1, qf1, z, 0, 0, 0);
    }
    // ---- V frags ----
    s8frag vf[8];
    #pragma unroll
    for (int nb = 0; nb < 4; nb++) {
      const int ro = pbo + (nb*16 + c16)*64;
      vf[nb*2]   = *(const s8frag*)&Vst[ro + sA*8];
      vf[nb*2+1] = *(const s8frag*)&Vst[ro + (sA^4)*8];
    }
    // ---- p = exp2(s); weight; pack; stash ----
    #pragma unroll
    for (int b = 0; b < 4; b++) {
      float4 wp4 = *(const float4*)&WP[j0 + b*16 + quad*4];
      float4 wn4 = *(const float4*)&WN[j0 + b*16 + quad*4];
      float p0 = exp2f(st[b][0]);
      float p1 = exp2f(st[b][1]);
      float p2 = exp2f(st[b][2]);
      float p3 = exp2f(st[b][3]);
      float a0 = p0*wp4.x, a1 = p1*wp4.y, a2 = p2*wp4.z, a3 = p3*wp4.w;
      float b0 = p0*wn4.x, b1 = p1*wn4.y, b2 = p2*wn4.z, b3 = p3*wn4.w;
      lp += (a0+a1)+(a2+a3);
      ln += (b0+b1)+(b2+b3);
      uint2 pu, nu;
      pu.x = pack_bf16(a0, a1); pu.y = pack_bf16(a2, a3);
      nu.x = pack_bf16(b0, b1); nu.y = pack_bf16(b2, b3);
      *(uint2*)&sm.P[w][0][c16][b*16 + quad*4] = pu;
      *(uint2*)&sm.P[w][1][c16][b*16 + quad*4] = nu;
    }
    // ---- PV ----
    s8frag ap0 = *(const s8frag*)&sm.P[w][0][c16][quad*8];
    s8frag ap1 = *(const s8frag*)&sm.P[w][0][c16][32 + quad*8];
    s8frag an0 = *(const s8frag*)&sm.P[w][1][c16][quad*8];
    s8frag an1 = *(const s8frag*)&sm.P[w][1][c16][32 + quad*8];
    #pragma unroll
    for (int nb = 0; nb < 4; nb++) {
      op[nb] = __builtin_amdgcn_mfma_f32_16x16x32_bf16(ap0, vf[nb*2],   op[nb], 0, 0, 0);
      op[nb] = __builtin_amdgcn_mfma_f32_16x16x32_bf16(ap1, vf[nb*2+1], op[nb], 0, 0, 0);
      on[nb] = __builtin_amdgcn_mfma_f32_16x16x32_bf16(an0, vf[nb*2],   on[nb], 0, 0, 0);
      on[nb] = __builtin_amdgcn_mfma_f32_16x16x32_bf16(an1, vf[nb*2+1], on[nb], 0, 0, 0);
    }
    pb ^= 1;
  }

  // ---- epilogue: write unnormalized partials ----
  lp += __shfl_xor(lp, 16, 64); lp += __shfl_xor(lp, 32, 64);
  ln += __shfl_xor(ln, 16, 64); ln += __shfl_xor(ln, 32, 64);
  if (quad == 0) {
    int iq = q0 + w*16 + c16;
    if (iq < TOK) {
      Lp[((size_t)half*NH + h)*NQROW + iq] = lp;
      Ln[((size_t)half*NH + h)*NQROW + iq] = ln;
    }
  }
  const int q_l = lane >> 2;
  const int db  = (lane & 3) * 16;
  const int iq = q0 + w*16 + q_l;
  // pos
  #pragma unroll
  for (int nb = 0; nb < 4; nb++)
    #pragma unroll
    for (int r = 0; r < 4; r++)
      sm.S[w][quad*4+r][nb*16+c16] = op[nb][r];
  float vp[16];
  #pragma unroll
  for (int i = 0; i < 16; i++) vp[i] = sm.S[w][q_l][db + i];
  // neg
  #pragma unroll
  for (int nb = 0; nb < 4; nb++)
    #pragma unroll
    for (int r = 0; r < 4; r++)
      sm.S[w][quad*4+r][nb*16+c16] = on[nb][r];
  float vn[16];
  #pragma unroll
  for (int i = 0; i < 16; i++) vn[i] = sm.S[w][q_l][db + i];

  if (iq < TOK) {
    unsigned pk[8], nk[8];
    #pragma unroll
    for (int i = 0; i < 8; i++) {
      pk[i] = pack_bf16(vp[2*i], vp[2*i+1]);
      nk[i] = pack_bf16(vn[2*i], vn[2*i+1]);
    }
    size_t off = (size_t)half*NQROW*CH + (size_t)iq*CH + h*HD + db;
    *(uint4*)(POp + off)     = make_uint4(pk[0], pk[1], pk[2], pk[3]);
    *(uint4*)(POp + off + 8) = make_uint4(pk[4], pk[5], pk[6], pk[7]);
    *(uint4*)(POn + off)     = make_uint4(nk[0], nk[1], nk[2], nk[3]);
    *(uint4*)(POn + off + 8) = make_uint4(nk[4], nk[5], nk[6], nk[7]);
  }
}

// ---------------- merge kernel: sum halves, divide, select, emit bf16 ---------------
__global__ __launch_bounds__(256) void merge_kernel(
    const ushort_t* __restrict__ POp, const ushort_t* __restrict__ POn,
    const float* __restrict__ Lp, const float* __restrict__ Ln,
    const int* __restrict__ cls, ushort_t* __restrict__ AObf)
{
  const int row = blockIdx.x;               // < TOK
  const int c4 = threadIdx.x * 4;
  const int h = c4 >> 6;
  const size_t o0 = (size_t)row*CH + c4;
  const size_t o1 = (size_t)NQROW*CH + o0;
  ushort4 p0 = *(const ushort4*)(POp + o0);
  ushort4 p1 = *(const ushort4*)(POp + o1);
  ushort4 n0 = *(const ushort4*)(POn + o0);
  ushort4 n1 = *(const ushort4*)(POn + o1);
  const float lpt = Lp[(size_t)h*NQROW + row] + Lp[(size_t)(NH+h)*NQROW + row];
  const float lnt = Ln[(size_t)h*NQROW + row] + Ln[(size_t)(NH+h)*NQROW + row];
  const float ilp = 1.f / lpt, iln = 1.f / lnt;
  const int cq = cls[row];
  float vp[4], vn[4], o[4];
  vp[0] = (bf2f(p0.x)+bf2f(p1.x))*ilp; vn[0] = (bf2f(n0.x)+bf2f(n1.x))*iln;
  vp[1] = (bf2f(p0.y)+bf2f(p1.y))*ilp; vn[1] = (bf2f(n0.y)+bf2f(n1.y))*iln;
  vp[2] = (bf2f(p0.z)+bf2f(p1.z))*ilp; vn[2] = (bf2f(n0.z)+bf2f(n1.z))*iln;
  vp[3] = (bf2f(p0.w)+bf2f(p1.w))*ilp; vn[3] = (bf2f(n0.w)+bf2f(n1.w))*iln;
  if (row < NREG) {
    #pragma unroll
    for (int i = 0; i < 4; i++) o[i] = 0.5f*(vp[i]+vn[i]);
  } else if (cq == 1) {
    #pragma unroll
    for (int i = 0; i < 4; i++) o[i] = vp[i];
  } else {
    #pragma unroll
    for (int i = 0; i < 4; i++) o[i] = vn[i];
  }
  uint2 pk;
  pk.x = pack_bf16(o[0], o[1]);
  pk.y = pack_bf16(o[2], o[3]);
  *(uint2*)(AObf + (size_t)row*CH + c4) = pk;
}

// ---------------- Proj GEMM via MFMA (bf16) -----------------------------------------
__global__ __launch_bounds__(256) void gemm_proj_mfma(
    const ushort_t* __restrict__ A, const ushort_t* __restrict__ WT,
    const float* __restrict__ bp, float* __restrict__ out)
{
  const int tid = threadIdx.x;
  const int w = tid >> 6, lane = tid & 63;
  const int quad = lane >> 4, c16 = lane & 15;
  const int n0 = blockIdx.x * 64;
  const int m0 = blockIdx.y * 64;
  const int ar = m0 + w*16 + c16;
  const ushort_t* ab = A + (size_t)ar*CH + quad*8;
  const ushort_t* wb0 = WT + (size_t)(n0 + c16)*CH + quad*8;
  f4frag acc[4];
  #pragma unroll
  for (int nb = 0; nb < 4; nb++) acc[nb] = (f4frag){0.f,0.f,0.f,0.f};
  #pragma unroll 2
  for (int k0 = 0; k0 < CH; k0 += 32) {
    s8frag a0 = *(const s8frag*)(ab + k0);
    #pragma unroll
    for (int nb = 0; nb < 4; nb++) {
      s8frag wh = *(const s8frag*)(wb0 + (size_t)nb*16*CH + k0);
      acc[nb] = __builtin_amdgcn_mfma_f32_16x16x32_bf16(a0, wh, acc[nb], 0, 0, 0);
    }
  }
  const int orow = m0 + w*16 + quad*4;
  #pragma unroll
  for (int nb = 0; nb < 4; nb++) {
    int n = n0 + nb*16 + c16;
    float bias = bp[n];
    #pragma unroll
    for (int r = 0; r < 4; r++) {
      int row = orow + r;
      if (row < TOK) out[(size_t)row*CH + n] = acc[nb][r] + bias;
    }
  }
}

extern "C" void kernel_launch(void* const* d_in, const int* in_sizes, int n_in,
                              void* d_out, int out_size, void* d_ws, size_t ws_size,
                              hipStream_t stream) {
  const float* x      = (const float*)d_in[0];
  const float* g_info = (const float*)d_in[1];
  const float* W_qkv  = (const float*)d_in[2];
  const float* W_proj = (const float*)d_in[3];
  const float* b_proj = (const float*)d_in[4];
  float* out = (float*)d_out;

  float* ws = (float*)d_ws;
  float* Qf  = ws;                                   // NH*TOK*HD
  float* SIM = Qf + (size_t)NH*TOK*HD;               // NTOK
  float* WP  = SIM + NTOK;                           // NPAD2
  float* WN  = WP + NPAD2;                           // NPAD2
  int*   CLS = (int*)(WN + NPAD2);                   // 2312
  float* LpB = (float*)(CLS + 2312);                 // 2*NH*NQROW
  float* LnB = LpB + (size_t)2*NH*NQROW;             // 2*NH*NQROW
  ushort_t* Xhi    = (ushort_t*)(LnB + (size_t)2*NH*NQROW);
  ushort_t* Xlo    = Xhi    + (size_t)NPADQ*CH;
  ushort_t* WqkvT  = Xlo    + (size_t)NPADQ*CH;      // 3072*1024
  ushort_t* WqkvLo = WqkvT  + (size_t)3*CH*CH;       // 1024*1024
  ushort_t* WprojT = WqkvLo + (size_t)CH*CH;         // 1024*1024
  ushort_t* Qbf    = WprojT + (size_t)CH*CH;         // NH*NPADQ*HD
  ushort_t* Kbf    = Qbf    + (size_t)NH*NPADQ*HD;   // NH*NPAD2*HD
  ushort_t* VTbf   = Kbf    + (size_t)NH*NPAD2*HD;   // NH*NPAD2*HD
  ushort_t* AObf   = VTbf   + (size_t)NH*NPAD2*HD;   // NPADQ*CH
  ushort_t* POp    = AObf   + (size_t)NPADQ*CH;      // 2*NQROW*CH
  ushort_t* POn    = POp    + (size_t)2*NQROW*CH;    // 2*NQROW*CH

  // zero K/V pad regions (rows/cols >= NPADQ never written by the GEMM)
  hipMemsetAsync(Kbf, 0, (size_t)2*NH*NPAD2*HD*sizeof(ushort_t), stream);

  split_x_kernel<<<dim3(NPADQ), 256, 0, stream>>>(x, Xhi, Xlo);
  pack_w_kernel<<<dim3(48, 16), 256, 0, stream>>>(W_qkv, 3*CH, WqkvT, WqkvLo, CH);
  pack_w_kernel<<<dim3(16, 16), 256, 0, stream>>>(W_proj, CH, WprojT, nullptr, 0);
  gemm_qkv_mfma<<<dim3(48, 38), 256, 0, stream>>>(Xhi, Xlo, WqkvT, WqkvLo,
                                                  Qf, Qbf, Kbf, VTbf);
  sim_kernel<<<dim3(576), 256, 0, stream>>>(Qf, g_info, SIM);
  mask_kernel<<<dim3(1), 256, 0, stream>>>(SIM, CLS, WP, WN);
  attn_kernel<<<dim3(37, NH, 2), 256, 0, stream>>>(Qbf, Kbf, VTbf, WP, WN,
                                                   POp, POn, LpB, LnB);
  merge_kernel<<<dim3(TOK), 256, 0, stream>>>(POp, POn, LpB, LnB, CLS, AObf);
  gemm_proj_mfma<<<dim3(16, 37), 256, 0, stream>>>(AObf, WprojT, b_proj, out);
}

// Round 8
// 330.711 us; speedup vs baseline: 1.5670x; 1.5670x over previous
//
#include <hip/hip_runtime.h>
#include <math.h>

#define TOK 2309
#define CH 1024
#define NH 16
#define HD 64
#define NREG 5
#define NTOK (TOK - NREG)    // 2304
#define NPADQ 2432           // 19*128 (query/M padding)
#define NPAD2 2560           // 40*64 (key padding)
#define HTILES 20            // K-tiles per half (attention split-K)
#define NQROW 2368           // 37*64 rows in attention output partials
#define QSCL 0.1803368801f   // 0.125 * log2(e)

typedef unsigned short ushort_t;
typedef __attribute__((ext_vector_type(8))) short s8frag;
typedef __attribute__((ext_vector_type(4))) float f4frag;

__device__ __forceinline__ float wredsum(float v){
  #pragma unroll
  for (int o = 32; o > 0; o >>= 1) v += __shfl_xor(v, o, 64);
  return v;
}

__device__ __forceinline__ unsigned short f2bf(float x){
  union { float f; unsigned u; } v; v.f = x;
  unsigned r = v.u + 0x7FFF + ((v.u >> 16) & 1);
  return (unsigned short)(r >> 16);
}
__device__ __forceinline__ float bf2f(unsigned short u){
  union { unsigned u32; float f; } v; v.u32 = ((unsigned)u) << 16;
  return v.f;
}
__device__ __forceinline__ unsigned pack_bf16(float lo, float hi){
  union { float f; unsigned u; } a, b;
  a.f = lo; b.f = hi;
  return __builtin_amdgcn_perm(b.u + 0x8000u, a.u + 0x8000u, 0x07060302u);
}
// async global->LDS 16B/lane; lds ptr must be wave-uniform (HW adds lane*16)
__device__ __forceinline__ void cp16(const ushort_t* g, ushort_t* l){
  __builtin_amdgcn_global_load_lds(
      (const __attribute__((address_space(1))) unsigned int*)g,
      (__attribute__((address_space(3))) unsigned int*)l, 16, 0, 0);
}

// ---------------- split X into hi/lo bf16 (rows padded to NPADQ with zeros) --------
__global__ __launch_bounds__(256) void split_x_kernel(
    const float* __restrict__ X, ushort_t* __restrict__ Xhi, ushort_t* __restrict__ Xlo)
{
  int row = blockIdx.x;
  int c4 = threadIdx.x * 4;
  ushort4 h4 = {0,0,0,0}, l4 = {0,0,0,0};
  if (row < TOK) {
    float4 v = *(const float4*)&X[(size_t)row*CH + c4];
    float vv[4] = {v.x, v.y, v.z, v.w};
    ushort_t hs[4], ls[4];
    #pragma unroll
    for (int i = 0; i < 4; i++) {
      hs[i] = f2bf(vv[i]);
      ls[i] = f2bf(vv[i] - bf2f(hs[i]));
    }
    h4.x=hs[0]; h4.y=hs[1]; h4.z=hs[2]; h4.w=hs[3];
    l4.x=ls[0]; l4.y=ls[1]; l4.z=ls[2]; l4.w=ls[3];
  }
  *(ushort4*)&Xhi[(size_t)row*CH + c4] = h4;
  *(ushort4*)&Xlo[(size_t)row*CH + c4] = l4;
}

// ---------------- transpose+split W: W(1024 x N) -> WT(N x 1024) bf16 (+lo) --------
__global__ __launch_bounds__(256) void pack_w_kernel(
    const float* __restrict__ W, const int N,
    ushort_t* __restrict__ WT, ushort_t* __restrict__ WloT, const int loN)
{
  __shared__ float T[64][68];
  const int tid = threadIdx.x;
  const int n0 = blockIdx.x * 64;
  const int k0 = blockIdx.y * 64;
  const int lr = tid >> 4;
  const int lc = (tid & 15) * 4;
  #pragma unroll
  for (int s = 0; s < 4; s++) {
    float4 v = *(const float4*)&W[(size_t)(k0 + lr + s*16) * N + n0 + lc];
    *(float4*)&T[lr + s*16][lc] = v;
  }
  __syncthreads();
  const int nl = tid >> 2;
  const int kc = (tid & 3) * 16;
  const bool dolo = (WloT != nullptr) && (n0 < loN);
  ushort_t* dh = WT + (size_t)(n0 + nl) * CH + k0 + kc;
  ushort_t* dl = WloT + (size_t)(n0 + nl) * CH + k0 + kc;
  #pragma unroll
  for (int g = 0; g < 4; g++) {
    float a = T[kc+g*4+0][nl], b = T[kc+g*4+1][nl];
    float c = T[kc+g*4+2][nl], d = T[kc+g*4+3][nl];
    ushort4 oh;
    oh.x=f2bf(a); oh.y=f2bf(b); oh.z=f2bf(c); oh.w=f2bf(d);
    *(ushort4*)&dh[g*4] = oh;
    if (dolo) {
      ushort4 ol;
      ol.x=f2bf(a-bf2f(oh.x)); ol.y=f2bf(b-bf2f(oh.y));
      ol.z=f2bf(c-bf2f(oh.z)); ol.w=f2bf(d-bf2f(oh.w));
      *(ushort4*)&dl[g*4] = ol;
    }
  }
}

// ---------------- QKV GEMM: m97-style 128x128 tile, LDS-staged, dbuf ----------------
__global__ __launch_bounds__(256) void gemm_qkv_mfma(
    const ushort_t* __restrict__ Xhi, const ushort_t* __restrict__ Xlo,
    const ushort_t* __restrict__ WhiT, const ushort_t* __restrict__ WloT,
    float* __restrict__ Qf, ushort_t* __restrict__ Qbf,
    ushort_t* __restrict__ Kbf, ushort_t* __restrict__ VTbf)
{
  __shared__ ushort_t LA[2][2][4096];   // [buf][hi/lo][128 rows x 32 k]
  __shared__ ushort_t LB[2][2][4096];
  const int tid = threadIdx.x;
  const int w = tid >> 6, lane = tid & 63;
  const int quad = lane >> 4, c16 = lane & 15;
  const int wm = w >> 1, wn = w & 1;
  const int nt = blockIdx.x, mt = blockIdx.y;
  const int n0 = nt * 128, m0 = mt * 128;
  const bool isQ = (nt < 8);

  const int srow = tid >> 2;
  const int g = (tid & 3) ^ ((tid >> 3) & 3);
  const size_t aoff = (size_t)(m0 + srow)*CH + g*8;
  const size_t boff = (size_t)(n0 + srow)*CH + g*8;
  const int lbase = (tid & 192) * 8;

  f4frag acc[4][4];
  #pragma unroll
  for (int mi = 0; mi < 4; mi++)
    #pragma unroll
    for (int nb = 0; nb < 4; nb++) acc[mi][nb] = (f4frag){0.f,0.f,0.f,0.f};

  const int soff = (quad ^ ((c16 >> 1) & 3)) * 8;
  int aro[4], bro[4];
  #pragma unroll
  for (int i = 0; i < 4; i++) {
    aro[i] = (wm*64 + i*16 + c16)*32 + soff;
    bro[i] = (wn*64 + i*16 + c16)*32 + soff;
  }

#define QKV_STAGE(KT, BUF) {                                                   \
    const int _k = (KT)*32;                                                    \
    cp16(Xhi  + aoff + _k,                 &LA[BUF][0][lbase]);                \
    cp16(Xhi  + aoff + _k + (size_t)64*CH, &LA[BUF][0][2048 + lbase]);         \
    cp16(WhiT + boff + _k,                 &LB[BUF][0][lbase]);                \
    cp16(WhiT + boff + _k + (size_t)64*CH, &LB[BUF][0][2048 + lbase]);         \
    if (isQ) {                                                                 \
      cp16(Xlo  + aoff + _k,                 &LA[BUF][1][lbase]);              \
      cp16(Xlo  + aoff + _k + (size_t)64*CH, &LA[BUF][1][2048 + lbase]);       \
      cp16(WloT + boff + _k,                 &LB[BUF][1][lbase]);              \
      cp16(WloT + boff + _k + (size_t)64*CH, &LB[BUF][1][2048 + lbase]);       \
    } }

  QKV_STAGE(0, 0);
  for (int kt = 0; kt < 32; kt++) {
    const int buf = kt & 1;
    __syncthreads();
    if (kt < 31) { QKV_STAGE(kt+1, buf^1); }
    s8frag a[4], b[4];
    #pragma unroll
    for (int i = 0; i < 4; i++) a[i] = *(const s8frag*)&LA[buf][0][aro[i]];
    #pragma unroll
    for (int i = 0; i < 4; i++) b[i] = *(const s8frag*)&LB[buf][0][bro[i]];
    #pragma unroll
    for (int mi = 0; mi < 4; mi++)
      #pragma unroll
      for (int nb = 0; nb < 4; nb++)
        acc[mi][nb] = __builtin_amdgcn_mfma_f32_16x16x32_bf16(a[mi], b[nb], acc[mi][nb], 0, 0, 0);
    if (isQ) {
      s8frag al[4], bl[4];
      #pragma unroll
      for (int i = 0; i < 4; i++) al[i] = *(const s8frag*)&LA[buf][1][aro[i]];
      #pragma unroll
      for (int i = 0; i < 4; i++) bl[i] = *(const s8frag*)&LB[buf][1][bro[i]];
      #pragma unroll
      for (int mi = 0; mi < 4; mi++)
        #pragma unroll
        for (int nb = 0; nb < 4; nb++) {
          acc[mi][nb] = __builtin_amdgcn_mfma_f32_16x16x32_bf16(a[mi],  bl[nb], acc[mi][nb], 0, 0, 0);
          acc[mi][nb] = __builtin_amdgcn_mfma_f32_16x16x32_bf16(al[mi], b[nb],  acc[mi][nb], 0, 0, 0);
        }
    }
  }
#undef QKV_STAGE

  const int three = (nt >= 16) ? 2 : (nt >= 8) ? 1 : 0;
  #pragma unroll
  for (int mi = 0; mi < 4; mi++) {
    const int orow = m0 + wm*64 + mi*16 + quad*4;
    if (three == 0) {
      #pragma unroll
      for (int nb = 0; nb < 4; nb++) {
        const int col = n0 + wn*64 + nb*16 + c16;
        const int h = (col >> 6) & 15, d = col & 63;
        float* qf = Qf + (size_t)h*TOK*HD;
        ushort_t* qb = Qbf + (size_t)h*NPADQ*HD;
        #pragma unroll
        for (int r = 0; r < 4; r++) {
          int row = orow + r;
          float v = (row < TOK) ? acc[mi][nb][r] : 0.f;
          if (row < TOK) qf[(size_t)row*HD + d] = v;
          qb[(size_t)row*HD + d] = f2bf(v * QSCL);
        }
      }
    } else if (three == 1) {
      #pragma unroll
      for (int nb = 0; nb < 4; nb++) {
        const int col = n0 + wn*64 + nb*16 + c16;
        const int h = (col >> 6) & 15, d = col & 63;
        ushort_t* kb = Kbf + (size_t)h*NPAD2*HD;
        #pragma unroll
        for (int r = 0; r < 4; r++) {
          int row = orow + r;
          float v = (row < TOK) ? acc[mi][nb][r] : 0.f;
          kb[(size_t)row*HD + d] = f2bf(v);
        }
      }
    } else {
      #pragma unroll
      for (int nb = 0; nb < 4; nb++) {
        const int col = n0 + wn*64 + nb*16 + c16;
        const int h = (col >> 6) & 15, d = col & 63;
        ushort_t* vt = VTbf + (size_t)h*HD*NPAD2;
        ushort4 o;
        o.x = f2bf((orow+0 < TOK) ? acc[mi][nb][0] : 0.f);
        o.y = f2bf((orow+1 < TOK) ? acc[mi][nb][1] : 0.f);
        o.z = f2bf((orow+2 < TOK) ? acc[mi][nb][2] : 0.f);
        o.w = f2bf((orow+3 < TOK) ? acc[mi][nb][3] : 0.f);
        *(ushort4*)&vt[(size_t)d*NPAD2 + orow] = o;
      }
    }
  }
}

// ---------------- sim kernel (fp32 Q) ----------------------------------------------
__global__ __launch_bounds__(256) void sim_kernel(
    const float* __restrict__ Q, const float* __restrict__ G, float* __restrict__ sim)
{
  const int tid = threadIdx.x;
  const int w = tid >> 6, lane = tid & 63;
  float qgn[NH];
  #pragma unroll
  for (int h = 0; h < NH; h++) {
    float g = G[h*HD + lane];
    float n2 = wredsum(g*g);
    qgn[h] = g / sqrtf(n2);
  }
  int it = blockIdx.x * 4 + w;
  if (it >= NTOK) return;
  int i = NREG + it;
  float acc = 0.f;
  #pragma unroll
  for (int h = 0; h < NH; h++) {
    float qv = Q[((size_t)h*TOK + i)*HD + lane];
    float dot = wredsum(qv * qgn[h]);
    float n2  = wredsum(qv * qv);
    acc += dot / sqrtf(n2);
  }
  if (lane == 0) sim[it] = acc * (1.0f/16.0f);
}

// ---------------- mask kernel ------------------------------------------------------
__global__ __launch_bounds__(256) void mask_kernel(
    const float* __restrict__ sim, int* __restrict__ cls,
    float* __restrict__ WP, float* __restrict__ WN)
{
  __shared__ float smn[256], smx[256];
  const int tid = threadIdx.x;
  float mn = 1e30f, mx = -1e30f;
  for (int i = tid; i < NTOK; i += 256) { float s = sim[i]; mn = fminf(mn, s); mx = fmaxf(mx, s); }
  smn[tid] = mn; smx[tid] = mx;
  __syncthreads();
  for (int off = 128; off > 0; off >>= 1) {
    if (tid < off) { smn[tid] = fminf(smn[tid], smn[tid+off]); smx[tid] = fmaxf(smx[tid], smx[tid+off]); }
    __syncthreads();
  }
  mn = smn[0]; mx = smx[0];
  float inv = 1.0f / (mx - mn);
  for (int j = tid; j < NPAD2; j += 256) {
    float wp = 0.f, wn = 0.f; int c = 0;
    if (j < NREG) { wp = 1.f; wn = 1.f; c = 2; }
    else if (j < TOK) {
      bool pos = ((sim[j-NREG] - mn) * inv) > 0.9f;
      c = pos ? 1 : 0;
      wp = pos ? 1.f : 0.f;
      wn = pos ? 0.f : 1.f;
    }
    WP[j] = wp; WN[j] = wn;
    if (j < TOK) cls[j] = c;
  }
}

// ---------------- MFMA flash attention, LDS-staged, split-K x2 across blocks --------
__global__ __launch_bounds__(256) void attn_kernel(
    const ushort_t* __restrict__ Qbf, const ushort_t* __restrict__ Kbf,
    const ushort_t* __restrict__ VTbf,
    const float* __restrict__ WP, const float* __restrict__ WN,
    ushort_t* __restrict__ POp, ushort_t* __restrict__ POn,
    float* __restrict__ Lp, float* __restrict__ Ln)
{
  __shared__ ushort_t Kst[2*4096];
  __shared__ ushort_t Vst[2*4096];
  __shared__ union { ushort_t P[4][2][16][72]; float S[4][16][72]; } sm;
  const int tid = threadIdx.x;
  const int w = tid >> 6, lane = tid & 63;
  const int quad = lane >> 4, c16 = lane & 15;
  const int h = blockIdx.y;
  const int half = blockIdx.z;
  const int q0 = blockIdx.x * 64;
  const ushort_t* Qh  = Qbf  + (size_t)h * NPADQ * HD;
  const ushort_t* Kh  = Kbf  + (size_t)h * NPAD2 * HD + (size_t)half * HTILES * 64 * HD;
  const ushort_t* VTh = VTbf + (size_t)h * HD * NPAD2;

  s8frag qf0 = *(const s8frag*)(Qh + (size_t)(q0 + w*16 + c16)*HD + quad*8);
  s8frag qf1 = *(const s8frag*)(Qh + (size_t)(q0 + w*16 + c16)*HD + 32 + quad*8);

  const int r1 = tid >> 3,         s1 = (tid & 7) ^ (r1 & 7);
  const int r2 = (tid + 256) >> 3, s2 = (tid & 7) ^ (r2 & 7);
  const ushort_t* gk1 = Kh + r1*HD + s1*8;
  const ushort_t* gk2 = Kh + r2*HD + s2*8;
  const ushort_t* gv1 = VTh + (size_t)r1*NPAD2 + half*(HTILES*64) + s1*8;
  const ushort_t* gv2 = VTh + (size_t)r2*NPAD2 + half*(HTILES*64) + s2*8;
  ushort_t* lk = &Kst[(tid & 192) * 8];
  ushort_t* lv = &Vst[(tid & 192) * 8];

  cp16(gk1, lk);        cp16(gk2, lk + 2048);
  cp16(gv1, lv);        cp16(gv2, lv + 2048);

  f4frag op[4], on[4];
  #pragma unroll
  for (int nb = 0; nb < 4; nb++) { op[nb] = (f4frag){0.f,0.f,0.f,0.f}; on[nb] = (f4frag){0.f,0.f,0.f,0.f}; }
  float lp = 0.f, ln = 0.f;
  const int sA = quad ^ (c16 & 7);

  int pb = 0;
  for (int t = 0; t < HTILES; t++) {
    __syncthreads();
    if (t < HTILES-1) {
      const int tn = t + 1;
      ushort_t* dk = lk + (pb^1)*4096;
      ushort_t* dv = lv + (pb^1)*4096;
      cp16(gk1 + tn*4096, dk);       cp16(gk2 + tn*4096, dk + 2048);
      cp16(gv1 + tn*64,   dv);       cp16(gv2 + tn*64,   dv + 2048);
    }
    const int j0 = half*(HTILES*64) + t*64;
    const int pbo = pb*4096;
    f4frag st[4];
    #pragma unroll
    for (int b = 0; b < 4; b++) {
      const int ro = pbo + (b*16 + c16)*64;
      s8frag kf0 = *(const s8frag*)&Kst[ro + sA*8];
      s8frag kf1 = *(const s8frag*)&Kst[ro + (sA^4)*8];
      f4frag z = (f4frag){0.f,0.f,0.f,0.f};
      z = __builtin_amdgcn_mfma_f32_16x16x32_bf16(kf0, qf0, z, 0, 0, 0);
      st[b] = __builtin_amdgcn_mfma_f32_16x16x32_bf16(kf1, qf1, z, 0, 0, 0);
    }
    s8frag vf[8];
    #pragma unroll
    for (int nb = 0; nb < 4; nb++) {
      const int ro = pbo + (nb*16 + c16)*64;
      vf[nb*2]   = *(const s8frag*)&Vst[ro + sA*8];
      vf[nb*2+1] = *(const s8frag*)&Vst[ro + (sA^4)*8];
    }
    #pragma unroll
    for (int b = 0; b < 4; b++) {
      float4 wp4 = *(const float4*)&WP[j0 + b*16 + quad*4];
      float4 wn4 = *(const float4*)&WN[j0 + b*16 + quad*4];
      float p0 = exp2f(st[b][0]);
      float p1 = exp2f(st[b][1]);
      float p2 = exp2f(st[b][2]);
      float p3 = exp2f(st[b][3]);
      float a0 = p0*wp4.x, a1 = p1*wp4.y, a2 = p2*wp4.z, a3 = p3*wp4.w;
      float b0 = p0*wn4.x, b1 = p1*wn4.y, b2 = p2*wn4.z, b3 = p3*wn4.w;
      lp += (a0+a1)+(a2+a3);
      ln += (b0+b1)+(b2+b3);
      uint2 pu, nu;
      pu.x = pack_bf16(a0, a1); pu.y = pack_bf16(a2, a3);
      nu.x = pack_bf16(b0, b1); nu.y = pack_bf16(b2, b3);
      *(uint2*)&sm.P[w][0][c16][b*16 + quad*4] = pu;
      *(uint2*)&sm.P[w][1][c16][b*16 + quad*4] = nu;
    }
    s8frag ap0 = *(const s8frag*)&sm.P[w][0][c16][quad*8];
    s8frag ap1 = *(const s8frag*)&sm.P[w][0][c16][32 + quad*8];
    s8frag an0 = *(const s8frag*)&sm.P[w][1][c16][quad*8];
    s8frag an1 = *(const s8frag*)&sm.P[w][1][c16][32 + quad*8];
    #pragma unroll
    for (int nb = 0; nb < 4; nb++) {
      op[nb] = __builtin_amdgcn_mfma_f32_16x16x32_bf16(ap0, vf[nb*2],   op[nb], 0, 0, 0);
      op[nb] = __builtin_amdgcn_mfma_f32_16x16x32_bf16(ap1, vf[nb*2+1], op[nb], 0, 0, 0);
      on[nb] = __builtin_amdgcn_mfma_f32_16x16x32_bf16(an0, vf[nb*2],   on[nb], 0, 0, 0);
      on[nb] = __builtin_amdgcn_mfma_f32_16x16x32_bf16(an1, vf[nb*2+1], on[nb], 0, 0, 0);
    }
    pb ^= 1;
  }

  lp += __shfl_xor(lp, 16, 64); lp += __shfl_xor(lp, 32, 64);
  ln += __shfl_xor(ln, 16, 64); ln += __shfl_xor(ln, 32, 64);
  if (quad == 0) {
    int iq = q0 + w*16 + c16;
    if (iq < TOK) {
      Lp[((size_t)half*NH + h)*NQROW + iq] = lp;
      Ln[((size_t)half*NH + h)*NQROW + iq] = ln;
    }
  }
  const int q_l = lane >> 2;
  const int db  = (lane & 3) * 16;
  const int iq = q0 + w*16 + q_l;
  #pragma unroll
  for (int nb = 0; nb < 4; nb++)
    #pragma unroll
    for (int r = 0; r < 4; r++)
      sm.S[w][quad*4+r][nb*16+c16] = op[nb][r];
  float vp[16];
  #pragma unroll
  for (int i = 0; i < 16; i++) vp[i] = sm.S[w][q_l][db + i];
  #pragma unroll
  for (int nb = 0; nb < 4; nb++)
    #pragma unroll
    for (int r = 0; r < 4; r++)
      sm.S[w][quad*4+r][nb*16+c16] = on[nb][r];
  float vn[16];
  #pragma unroll
  for (int i = 0; i < 16; i++) vn[i] = sm.S[w][q_l][db + i];

  if (iq < TOK) {
    unsigned pk[8], nk[8];
    #pragma unroll
    for (int i = 0; i < 8; i++) {
      pk[i] = pack_bf16(vp[2*i], vp[2*i+1]);
      nk[i] = pack_bf16(vn[2*i], vn[2*i+1]);
    }
    size_t off = (size_t)half*NQROW*CH + (size_t)iq*CH + h*HD + db;
    *(uint4*)(POp + off)     = make_uint4(pk[0], pk[1], pk[2], pk[3]);
    *(uint4*)(POp + off + 8) = make_uint4(pk[4], pk[5], pk[6], pk[7]);
    *(uint4*)(POn + off)     = make_uint4(nk[0], nk[1], nk[2], nk[3]);
    *(uint4*)(POn + off + 8) = make_uint4(nk[4], nk[5], nk[6], nk[7]);
  }
}

// ---------------- merge kernel ------------------------------------------------------
__global__ __launch_bounds__(256) void merge_kernel(
    const ushort_t* __restrict__ POp, const ushort_t* __restrict__ POn,
    const float* __restrict__ Lp, const float* __restrict__ Ln,
    const int* __restrict__ cls, ushort_t* __restrict__ AObf)
{
  const int row = blockIdx.x;
  const int c4 = threadIdx.x * 4;
  const int h = c4 >> 6;
  const size_t o0 = (size_t)row*CH + c4;
  const size_t o1 = (size_t)NQROW*CH + o0;
  ushort4 p0 = *(const ushort4*)(POp + o0);
  ushort4 p1 = *(const ushort4*)(POp + o1);
  ushort4 n0 = *(const ushort4*)(POn + o0);
  ushort4 n1 = *(const ushort4*)(POn + o1);
  const float lpt = Lp[(size_t)h*NQROW + row] + Lp[(size_t)(NH+h)*NQROW + row];
  const float lnt = Ln[(size_t)h*NQROW + row] + Ln[(size_t)(NH+h)*NQROW + row];
  const float ilp = 1.f / lpt, iln = 1.f / lnt;
  const int cq = cls[row];
  float vp[4], vn[4], o[4];
  vp[0] = (bf2f(p0.x)+bf2f(p1.x))*ilp; vn[0] = (bf2f(n0.x)+bf2f(n1.x))*iln;
  vp[1] = (bf2f(p0.y)+bf2f(p1.y))*ilp; vn[1] = (bf2f(n0.y)+bf2f(n1.y))*iln;
  vp[2] = (bf2f(p0.z)+bf2f(p1.z))*ilp; vn[2] = (bf2f(n0.z)+bf2f(n1.z))*iln;
  vp[3] = (bf2f(p0.w)+bf2f(p1.w))*ilp; vn[3] = (bf2f(n0.w)+bf2f(n1.w))*iln;
  if (row < NREG) {
    #pragma unroll
    for (int i = 0; i < 4; i++) o[i] = 0.5f*(vp[i]+vn[i]);
  } else if (cq == 1) {
    #pragma unroll
    for (int i = 0; i < 4; i++) o[i] = vp[i];
  } else {
    #pragma unroll
    for (int i = 0; i < 4; i++) o[i] = vn[i];
  }
  uint2 pk;
  pk.x = pack_bf16(o[0], o[1]);
  pk.y = pack_bf16(o[2], o[3]);
  *(uint2*)(AObf + (size_t)row*CH + c4) = pk;
}

// ---------------- Proj GEMM: m97-style 128x128 tile, LDS-staged, dbuf ---------------
__global__ __launch_bounds__(256) void gemm_proj_mfma(
    const ushort_t* __restrict__ A, const ushort_t* __restrict__ WT,
    const float* __restrict__ bp, float* __restrict__ out)
{
  __shared__ ushort_t LA[2][4096];
  __shared__ ushort_t LB[2][4096];
  const int tid = threadIdx.x;
  const int w = tid >> 6, lane = tid & 63;
  const int quad = lane >> 4, c16 = lane & 15;
  const int wm = w >> 1, wn = w & 1;
  const int nt = blockIdx.x, mt = blockIdx.y;
  const int n0 = nt * 128, m0 = mt * 128;

  const int srow = tid >> 2;
  const int g = (tid & 3) ^ ((tid >> 3) & 3);
  const size_t aoff = (size_t)(m0 + srow)*CH + g*8;
  const size_t boff = (size_t)(n0 + srow)*CH + g*8;
  const int lbase = (tid & 192) * 8;

  f4frag acc[4][4];
  #pragma unroll
  for (int mi = 0; mi < 4; mi++)
    #pragma unroll
    for (int nb = 0; nb < 4; nb++) acc[mi][nb] = (f4frag){0.f,0.f,0.f,0.f};

  const int soff = (quad ^ ((c16 >> 1) & 3)) * 8;
  int aro[4], bro[4];
  #pragma unroll
  for (int i = 0; i < 4; i++) {
    aro[i] = (wm*64 + i*16 + c16)*32 + soff;
    bro[i] = (wn*64 + i*16 + c16)*32 + soff;
  }

#define PROJ_STAGE(KT, BUF) {                                                  \
    const int _k = (KT)*32;                                                    \
    cp16(A  + aoff + _k,                 &LA[BUF][lbase]);                     \
    cp16(A  + aoff + _k + (size_t)64*CH, &LA[BUF][2048 + lbase]);              \
    cp16(WT + boff + _k,                 &LB[BUF][lbase]);                     \
    cp16(WT + boff + _k + (size_t)64*CH, &LB[BUF][2048 + lbase]);              \
    }

  PROJ_STAGE(0, 0);
  for (int kt = 0; kt < 32; kt++) {
    const int buf = kt & 1;
    __syncthreads();
    if (kt < 31) { PROJ_STAGE(kt+1, buf^1); }
    s8frag a[4], b[4];
    #pragma unroll
    for (int i = 0; i < 4; i++) a[i] = *(const s8frag*)&LA[buf][aro[i]];
    #pragma unroll
    for (int i = 0; i < 4; i++) b[i] = *(const s8frag*)&LB[buf][bro[i]];
    #pragma unroll
    for (int mi = 0; mi < 4; mi++)
      #pragma unroll
      for (int nb = 0; nb < 4; nb++)
        acc[mi][nb] = __builtin_amdgcn_mfma_f32_16x16x32_bf16(a[mi], b[nb], acc[mi][nb], 0, 0, 0);
  }
#undef PROJ_STAGE

  #pragma unroll
  for (int mi = 0; mi < 4; mi++) {
    const int orow = m0 + wm*64 + mi*16 + quad*4;
    #pragma unroll
    for (int nb = 0; nb < 4; nb++) {
      const int col = n0 + wn*64 + nb*16 + c16;
      const float bias = bp[col];
      #pragma unroll
      for (int r = 0; r < 4; r++) {
        int row = orow + r;
        if (row < TOK) out[(size_t)row*CH + col] = acc[mi][nb][r] + bias;
      }
    }
  }
}

extern "C" void kernel_launch(void* const* d_in, const int* in_sizes, int n_in,
                              void* d_out, int out_size, void* d_ws, size_t ws_size,
                              hipStream_t stream) {
  const float* x      = (const float*)d_in[0];
  const float* g_info = (const float*)d_in[1];
  const float* W_qkv  = (const float*)d_in[2];
  const float* W_proj = (const float*)d_in[3];
  const float* b_proj = (const float*)d_in[4];
  float* out = (float*)d_out;

  float* ws = (float*)d_ws;
  float* Qf  = ws;                                   // NH*TOK*HD
  float* SIM = Qf + (size_t)NH*TOK*HD;               // NTOK
  float* WP  = SIM + NTOK;                           // NPAD2
  float* WN  = WP + NPAD2;                           // NPAD2
  int*   CLS = (int*)(WN + NPAD2);                   // 2312
  float* LpB = (float*)(CLS + 2312);                 // 2*NH*NQROW
  float* LnB = LpB + (size_t)2*NH*NQROW;             // 2*NH*NQROW
  ushort_t* Xhi    = (ushort_t*)(LnB + (size_t)2*NH*NQROW);
  ushort_t* Xlo    = Xhi    + (size_t)NPADQ*CH;
  ushort_t* WqkvT  = Xlo    + (size_t)NPADQ*CH;      // 3072*1024
  ushort_t* WqkvLo = WqkvT  + (size_t)3*CH*CH;       // 1024*1024
  ushort_t* WprojT = WqkvLo + (size_t)CH*CH;         // 1024*1024
  ushort_t* Qbf    = WprojT + (size_t)CH*CH;         // NH*NPADQ*HD
  ushort_t* Kbf    = Qbf    + (size_t)NH*NPADQ*HD;   // NH*NPAD2*HD
  ushort_t* VTbf   = Kbf    + (size_t)NH*NPAD2*HD;   // NH*NPAD2*HD
  ushort_t* AObf   = VTbf   + (size_t)NH*NPAD2*HD;   // NPADQ*CH
  ushort_t* POp    = AObf   + (size_t)NPADQ*CH;      // 2*NQROW*CH
  ushort_t* POn    = POp    + (size_t)2*NQROW*CH;    // 2*NQROW*CH

  hipMemsetAsync(Kbf, 0, (size_t)2*NH*NPAD2*HD*sizeof(ushort_t), stream);

  split_x_kernel<<<dim3(NPADQ), 256, 0, stream>>>(x, Xhi, Xlo);
  pack_w_kernel<<<dim3(48, 16), 256, 0, stream>>>(W_qkv, 3*CH, WqkvT, WqkvLo, CH);
  pack_w_kernel<<<dim3(16, 16), 256, 0, stream>>>(W_proj, CH, WprojT, nullptr, 0);
  gemm_qkv_mfma<<<dim3(24, 19), 256, 0, stream>>>(Xhi, Xlo, WqkvT, WqkvLo,
                                                  Qf, Qbf, Kbf, VTbf);
  sim_kernel<<<dim3(576), 256, 0, stream>>>(Qf, g_info, SIM);
  mask_kernel<<<dim3(1), 256, 0, stream>>>(SIM, CLS, WP, WN);
  attn_kernel<<<dim3(37, NH, 2), 256, 0, stream>>>(Qbf, Kbf, VTbf, WP, WN,
                                                   POp, POn, LpB, LnB);
  merge_kernel<<<dim3(TOK), 256, 0, stream>>>(POp, POn, LpB, LnB, CLS, AObf);
  gemm_proj_mfma<<<dim3(8, 19), 256, 0, stream>>>(AObf, WprojT, b_proj, out);
}

// Round 10
// 281.484 us; speedup vs baseline: 1.8411x; 1.1749x over previous
//
#include <hip/hip_runtime.h>
#include <math.h>

#define TOK 2309
#define CH 1024
#define NH 16
#define HD 64
#define NREG 5
#define NTOK (TOK - NREG)    // 2304
#define NPADQ 2432           // 19*128 (query/M padding)
#define NPAD2 2560           // 40*64 (key padding) -> 40 key tiles
#define NKT 40
#define HTILES 20            // K-tiles per half (attention split-K)
#define NQROW 2368           // 37*64 rows in attention output partials
#define QSCL 0.1803368801f   // 0.125 * log2(e)

typedef unsigned short ushort_t;
typedef unsigned char uchar_t;
typedef __attribute__((ext_vector_type(8))) short s8frag;
typedef __attribute__((ext_vector_type(4))) float f4frag;
typedef __attribute__((ext_vector_type(2))) long ll2;

__device__ __forceinline__ float wredsum(float v){
  #pragma unroll
  for (int o = 32; o > 0; o >>= 1) v += __shfl_xor(v, o, 64);
  return v;
}

__device__ __forceinline__ unsigned short f2bf(float x){
  union { float f; unsigned u; } v; v.f = x;
  unsigned r = v.u + 0x7FFF + ((v.u >> 16) & 1);
  return (unsigned short)(r >> 16);
}
__device__ __forceinline__ float bf2f(unsigned short u){
  union { unsigned u32; float f; } v; v.u32 = ((unsigned)u) << 16;
  return v.f;
}
__device__ __forceinline__ unsigned pack_bf16(float lo, float hi){
  union { float f; unsigned u; } a, b;
  a.f = lo; b.f = hi;
  return __builtin_amdgcn_perm(b.u + 0x8000u, a.u + 0x8000u, 0x07060302u);
}
__device__ __forceinline__ uchar_t f2fp8(float x){
  return (uchar_t)(__builtin_amdgcn_cvt_pk_fp8_f32(x, x, 0, false) & 0xff);
}
// async global->LDS 16B/lane; lds ptr must be wave-uniform (HW adds lane*16)
__device__ __forceinline__ void cp16(const void* g, void* l){
  __builtin_amdgcn_global_load_lds(
      (const __attribute__((address_space(1))) unsigned int*)g,
      (__attribute__((address_space(3))) unsigned int*)l, 16, 0, 0);
}

// ---------------- split X into hi/lo bf16 (rows padded to NPADQ with zeros) --------
__global__ __launch_bounds__(256) void split_x_kernel(
    const float* __restrict__ X, ushort_t* __restrict__ Xhi, ushort_t* __restrict__ Xlo)
{
  int row = blockIdx.x;
  int c4 = threadIdx.x * 4;
  ushort4 h4 = {0,0,0,0}, l4 = {0,0,0,0};
  if (row < TOK) {
    float4 v = *(const float4*)&X[(size_t)row*CH + c4];
    float vv[4] = {v.x, v.y, v.z, v.w};
    ushort_t hs[4], ls[4];
    #pragma unroll
    for (int i = 0; i < 4; i++) {
      hs[i] = f2bf(vv[i]);
      ls[i] = f2bf(vv[i] - bf2f(hs[i]));
    }
    h4.x=hs[0]; h4.y=hs[1]; h4.z=hs[2]; h4.w=hs[3];
    l4.x=ls[0]; l4.y=ls[1]; l4.z=ls[2]; l4.w=ls[3];
  }
  *(ushort4*)&Xhi[(size_t)row*CH + c4] = h4;
  *(ushort4*)&Xlo[(size_t)row*CH + c4] = l4;
}

// ---------------- transpose+split W: W(1024 x N) -> WT(N x 1024) bf16 (+lo) --------
__global__ __launch_bounds__(256) void pack_w_kernel(
    const float* __restrict__ W, const int N,
    ushort_t* __restrict__ WT, ushort_t* __restrict__ WloT, const int loN)
{
  __shared__ float T[64][68];
  const int tid = threadIdx.x;
  const int n0 = blockIdx.x * 64;
  const int k0 = blockIdx.y * 64;
  const int lr = tid >> 4;
  const int lc = (tid & 15) * 4;
  #pragma unroll
  for (int s = 0; s < 4; s++) {
    float4 v = *(const float4*)&W[(size_t)(k0 + lr + s*16) * N + n0 + lc];
    *(float4*)&T[lr + s*16][lc] = v;
  }
  __syncthreads();
  const int nl = tid >> 2;
  const int kc = (tid & 3) * 16;
  const bool dolo = (WloT != nullptr) && (n0 < loN);
  ushort_t* dh = WT + (size_t)(n0 + nl) * CH + k0 + kc;
  ushort_t* dl = WloT + (size_t)(n0 + nl) * CH + k0 + kc;
  #pragma unroll
  for (int g = 0; g < 4; g++) {
    float a = T[kc+g*4+0][nl], b = T[kc+g*4+1][nl];
    float c = T[kc+g*4+2][nl], d = T[kc+g*4+3][nl];
    ushort4 oh;
    oh.x=f2bf(a); oh.y=f2bf(b); oh.z=f2bf(c); oh.w=f2bf(d);
    *(ushort4*)&dh[g*4] = oh;
    if (dolo) {
      ushort4 ol;
      ol.x=f2bf(a-bf2f(oh.x)); ol.y=f2bf(b-bf2f(oh.y));
      ol.z=f2bf(c-bf2f(oh.z)); ol.w=f2bf(d-bf2f(oh.w));
      *(ushort4*)&dl[g*4] = ol;
    }
  }
}

// ---------------- QKV GEMM: 128x128 tile, LDS-staged dbuf ---------------------------
// Q -> Qf fp32 + Q8 fp8 (unscaled); K -> K8 fp8 frag-major tiles; V -> Vbf bf16
// frag-major tiles:
//  K8[h][tile][b][lane][16B]: lane=(quadK*16+c16K) holds K[key=tile*64+b*16+c16K]
//    [d=quadK*8..+8] bytes0-7, d=32+quadK*8..+8 bytes8-15
//  Vbf[h][tile][nb][half][lane][16B]: lane=(quadV*16+c16V) holds
//    V[j=tile*64+half*32+quadV*8..+8][d=nb*16+c16V] as 8 bf16
__global__ __launch_bounds__(256) void gemm_qkv_mfma(
    const ushort_t* __restrict__ Xhi, const ushort_t* __restrict__ Xlo,
    const ushort_t* __restrict__ WhiT, const ushort_t* __restrict__ WloT,
    float* __restrict__ Qf, uchar_t* __restrict__ Q8,
    uchar_t* __restrict__ K8, ushort_t* __restrict__ Vbf)
{
  __shared__ ushort_t LA[2][2][4096];
  __shared__ ushort_t LB[2][2][4096];
  const int tid = threadIdx.x;
  const int w = tid >> 6, lane = tid & 63;
  const int quad = lane >> 4, c16 = lane & 15;
  const int wm = w >> 1, wn = w & 1;
  const int nt = blockIdx.x, mt = blockIdx.y;
  const int n0 = nt * 128, m0 = mt * 128;
  const bool isQ = (nt < 8);

  const int srow = tid >> 2;
  const int g = (tid & 3) ^ ((tid >> 3) & 3);
  const size_t aoff = (size_t)(m0 + srow)*CH + g*8;
  const size_t boff = (size_t)(n0 + srow)*CH + g*8;
  const int lbase = (tid & 192) * 8;

  f4frag acc[4][4];
  #pragma unroll
  for (int mi = 0; mi < 4; mi++)
    #pragma unroll
    for (int nb = 0; nb < 4; nb++) acc[mi][nb] = (f4frag){0.f,0.f,0.f,0.f};

  const int soff = (quad ^ ((c16 >> 1) & 3)) * 8;
  int aro[4], bro[4];
  #pragma unroll
  for (int i = 0; i < 4; i++) {
    aro[i] = (wm*64 + i*16 + c16)*32 + soff;
    bro[i] = (wn*64 + i*16 + c16)*32 + soff;
  }

#define QKV_STAGE(KT, BUF) {                                                   \
    const int _k = (KT)*32;                                                    \
    cp16(Xhi  + aoff + _k,                 &LA[BUF][0][lbase]);                \
    cp16(Xhi  + aoff + _k + (size_t)64*CH, &LA[BUF][0][2048 + lbase]);         \
    cp16(WhiT + boff + _k,                 &LB[BUF][0][lbase]);                \
    cp16(WhiT + boff + _k + (size_t)64*CH, &LB[BUF][0][2048 + lbase]);         \
    if (isQ) {                                                                 \
      cp16(Xlo  + aoff + _k,                 &LA[BUF][1][lbase]);              \
      cp16(Xlo  + aoff + _k + (size_t)64*CH, &LA[BUF][1][2048 + lbase]);       \
      cp16(WloT + boff + _k,                 &LB[BUF][1][lbase]);              \
      cp16(WloT + boff + _k + (size_t)64*CH, &LB[BUF][1][2048 + lbase]);       \
    } }

  QKV_STAGE(0, 0);
  for (int kt = 0; kt < 32; kt++) {
    const int buf = kt & 1;
    __syncthreads();
    if (kt < 31) { QKV_STAGE(kt+1, buf^1); }
    s8frag a[4], b[4];
    #pragma unroll
    for (int i = 0; i < 4; i++) a[i] = *(const s8frag*)&LA[buf][0][aro[i]];
    #pragma unroll
    for (int i = 0; i < 4; i++) b[i] = *(const s8frag*)&LB[buf][0][bro[i]];
    #pragma unroll
    for (int mi = 0; mi < 4; mi++)
      #pragma unroll
      for (int nb = 0; nb < 4; nb++)
        acc[mi][nb] = __builtin_amdgcn_mfma_f32_16x16x32_bf16(a[mi], b[nb], acc[mi][nb], 0, 0, 0);
    if (isQ) {
      s8frag al[4], bl[4];
      #pragma unroll
      for (int i = 0; i < 4; i++) al[i] = *(const s8frag*)&LA[buf][1][aro[i]];
      #pragma unroll
      for (int i = 0; i < 4; i++) bl[i] = *(const s8frag*)&LB[buf][1][bro[i]];
      #pragma unroll
      for (int mi = 0; mi < 4; mi++)
        #pragma unroll
        for (int nb = 0; nb < 4; nb++) {
          acc[mi][nb] = __builtin_amdgcn_mfma_f32_16x16x32_bf16(a[mi],  bl[nb], acc[mi][nb], 0, 0, 0);
          acc[mi][nb] = __builtin_amdgcn_mfma_f32_16x16x32_bf16(al[mi], b[nb],  acc[mi][nb], 0, 0, 0);
        }
    }
  }
#undef QKV_STAGE

  const int three = (nt >= 16) ? 2 : (nt >= 8) ? 1 : 0;
  #pragma unroll
  for (int mi = 0; mi < 4; mi++) {
    const int orow = m0 + wm*64 + mi*16 + quad*4;
    if (three == 0) {
      #pragma unroll
      for (int nb = 0; nb < 4; nb++) {
        const int col = n0 + wn*64 + nb*16 + c16;
        const int h = (col >> 6) & 15, d = col & 63;
        float* qf = Qf + (size_t)h*TOK*HD;
        uchar_t* q8 = Q8 + (size_t)h*NPADQ*64;
        #pragma unroll
        for (int r = 0; r < 4; r++) {
          int row = orow + r;
          float v = (row < TOK) ? acc[mi][nb][r] : 0.f;
          if (row < TOK) qf[(size_t)row*HD + d] = v;
          q8[(size_t)row*64 + d] = f2fp8(v);
        }
      }
    } else if (three == 1) {
      #pragma unroll
      for (int nb = 0; nb < 4; nb++) {
        const int col = n0 + wn*64 + nb*16 + c16;
        const int h = (col >> 6) & 15;
        const int quadK = ((nb & 1) * 2) + (c16 >> 3);
        const int byteoff = (nb >> 1) * 8 + (c16 & 7);
        uchar_t* base = K8 + (size_t)h*NKT*4096;
        #pragma unroll
        for (int r = 0; r < 4; r++) {
          int row = orow + r;
          float v = (row < TOK) ? acc[mi][nb][r] : 0.f;
          int tile = row >> 6, b = (row >> 4) & 3, c16K = row & 15;
          base[(size_t)tile*4096 + b*1024 + (quadK*16 + c16K)*16 + byteoff] = f2fp8(v);
        }
      }
    } else {
      const int tile  = orow >> 6;
      const int vhalf = (orow >> 5) & 1;
      const int quadV = (orow >> 3) & 3;
      const int b0    = (orow & 7) * 2;     // 0 or 8 bytes within lane slot
      #pragma unroll
      for (int nb = 0; nb < 4; nb++) {
        const int col = n0 + wn*64 + nb*16 + c16;
        const int h = (col >> 6) & 15;
        const int nbv = (col >> 4) & 3, c16V = col & 15;
        ushort_t* base = Vbf + (size_t)h*NKT*4096;   // 4096 ushorts = 8192 B per tile
        ushort4 o;
        o.x = f2bf((orow+0 < TOK) ? acc[mi][nb][0] : 0.f);
        o.y = f2bf((orow+1 < TOK) ? acc[mi][nb][1] : 0.f);
        o.z = f2bf((orow+2 < TOK) ? acc[mi][nb][2] : 0.f);
        o.w = f2bf((orow+3 < TOK) ? acc[mi][nb][3] : 0.f);
        *(ushort4*)&base[(size_t)tile*4096 + nbv*1024 + vhalf*512
                         + (quadV*16 + c16V)*8 + (b0 >> 1)] = o;
      }
    }
  }
}

// ---------------- sim kernel (fp32 Q) ----------------------------------------------
__global__ __launch_bounds__(256) void sim_kernel(
    const float* __restrict__ Q, const float* __restrict__ G, float* __restrict__ sim)
{
  const int tid = threadIdx.x;
  const int w = tid >> 6, lane = tid & 63;
  float qgn[NH];
  #pragma unroll
  for (int h = 0; h < NH; h++) {
    float g = G[h*HD + lane];
    float n2 = wredsum(g*g);
    qgn[h] = g / sqrtf(n2);
  }
  int it = blockIdx.x * 4 + w;
  if (it >= NTOK) return;
  int i = NREG + it;
  float acc = 0.f;
  #pragma unroll
  for (int h = 0; h < NH; h++) {
    float qv = Q[((size_t)h*TOK + i)*HD + lane];
    float dot = wredsum(qv * qgn[h]);
    float n2  = wredsum(qv * qv);
    acc += dot / sqrtf(n2);
  }
  if (lane == 0) sim[it] = acc * (1.0f/16.0f);
}

// ---------------- mask kernel ------------------------------------------------------
__global__ __launch_bounds__(256) void mask_kernel(
    const float* __restrict__ sim, int* __restrict__ cls,
    float* __restrict__ WP, float* __restrict__ WN)
{
  __shared__ float smn[256], smx[256];
  const int tid = threadIdx.x;
  float mn = 1e30f, mx = -1e30f;
  for (int i = tid; i < NTOK; i += 256) { float s = sim[i]; mn = fminf(mn, s); mx = fmaxf(mx, s); }
  smn[tid] = mn; smx[tid] = mx;
  __syncthreads();
  for (int off = 128; off > 0; off >>= 1) {
    if (tid < off) { smn[tid] = fminf(smn[tid], smn[tid+off]); smx[tid] = fmaxf(smx[tid], smx[tid+off]); }
    __syncthreads();
  }
  mn = smn[0]; mx = smx[0];
  float inv = 1.0f / (mx - mn);
  for (int j = tid; j < NPAD2; j += 256) {
    float wp = 0.f, wn = 0.f; int c = 0;
    if (j < NREG) { wp = 1.f; wn = 1.f; c = 2; }
    else if (j < TOK) {
      bool pos = ((sim[j-NREG] - mn) * inv) > 0.9f;
      c = pos ? 1 : 0;
      wp = pos ? 1.f : 0.f;
      wn = pos ? 0.f : 1.f;
    }
    WP[j] = wp; WN[j] = wn;
    if (j < TOK) cls[j] = c;
  }
}

// ---------------- mixed-precision flash attention: fp8 QK, bf16 PV ------------------
// LDS carve: [0,8K) K dbuf fp8 | [8K,24K) V dbuf bf16 | [24K,40K) P bf16 per-wave.
// Epilogue scratch overlays [0,18.4K) after a barrier.
__global__ __launch_bounds__(256) void attn_kernel(
    const uchar_t* __restrict__ Q8, const uchar_t* __restrict__ K8,
    const ushort_t* __restrict__ Vbf,
    const float* __restrict__ WP, const float* __restrict__ WN,
    ushort_t* __restrict__ POp, ushort_t* __restrict__ POn,
    float* __restrict__ Lp, float* __restrict__ Ln)
{
  __shared__ __align__(16) uchar_t smem[40960];
  uchar_t* Kst = smem;                 // [2][4096]
  uchar_t* Vst = smem + 8192;          // [2][8192]
  const int tid = threadIdx.x;
  const int w = tid >> 6, lane = tid & 63;
  const int quad = lane >> 4, c16 = lane & 15;
  uchar_t* Pw  = smem + 24576 + w*4096;   // pos: [0,2K), neg: [2K,4K)
  const int h = blockIdx.y;
  const int half = blockIdx.z;
  const int q0 = blockIdx.x * 64;

  const uchar_t* Qh = Q8 + (size_t)h * NPADQ * 64;
  const uchar_t* gk = K8 + ((size_t)h*NKT + half*HTILES)*4096 + tid*16;
  const uchar_t* gv = (const uchar_t*)Vbf + ((size_t)h*NKT + half*HTILES)*8192 + tid*16;
  const int lw = w * 1024;   // wave-uniform LDS offset for cp16

  const uchar_t* qp = Qh + (size_t)(q0 + w*16 + c16)*64 + quad*8;
  const long qf0 = *(const long*)(qp);
  const long qf1 = *(const long*)(qp + 32);

  f4frag op[4], on[4];
  #pragma unroll
  for (int nb = 0; nb < 4; nb++) { op[nb] = (f4frag){0.f,0.f,0.f,0.f}; on[nb] = (f4frag){0.f,0.f,0.f,0.f}; }
  float lp = 0.f, ln = 0.f;

  cp16(gk, Kst + lw);
  cp16(gv, Vst + lw);
  cp16(gv + 4096, Vst + 4096 + lw);

  int pb = 0;
  for (int t = 0; t < HTILES; t++) {
    __syncthreads();
    if (t < HTILES-1) {
      cp16(gk + (size_t)(t+1)*4096, Kst + (pb^1)*4096 + lw);
      cp16(gv + (size_t)(t+1)*8192,        Vst + (pb^1)*8192 + lw);
      cp16(gv + (size_t)(t+1)*8192 + 4096, Vst + (pb^1)*8192 + 4096 + lw);
    }
    const int j0 = half*(HTILES*64) + t*64;
    // ---- QK fp8 (A=K frag-major, B=Q) ----
    f4frag st[4];
    #pragma unroll
    for (int b = 0; b < 4; b++) {
      ll2 kv = *(const ll2*)&Kst[pb*4096 + b*1024 + lane*16];
      f4frag z = (f4frag){0.f,0.f,0.f,0.f};
      z     = __builtin_amdgcn_mfma_f32_16x16x32_fp8_fp8(kv.x, qf0, z, 0, 0, 0);
      st[b] = __builtin_amdgcn_mfma_f32_16x16x32_fp8_fp8(kv.y, qf1, z, 0, 0, 0);
    }
    // ---- V bf16 frags ----
    s8frag vf0[4], vf1[4];
    #pragma unroll
    for (int nb = 0; nb < 4; nb++) {
      vf0[nb] = *(const s8frag*)&Vst[pb*8192 + nb*2048 + lane*16];
      vf1[nb] = *(const s8frag*)&Vst[pb*8192 + nb*2048 + 1024 + lane*16];
    }
    // ---- p = exp2(s*QSCL); weight; bf16-pack; frag-major P store ----
    #pragma unroll
    for (int b = 0; b < 4; b++) {
      float4 wp4 = *(const float4*)&WP[j0 + b*16 + quad*4];
      float4 wn4 = *(const float4*)&WN[j0 + b*16 + quad*4];
      float p0 = exp2f(st[b][0] * QSCL);
      float p1 = exp2f(st[b][1] * QSCL);
      float p2 = exp2f(st[b][2] * QSCL);
      float p3 = exp2f(st[b][3] * QSCL);
      float a0 = p0*wp4.x, a1 = p1*wp4.y, a2 = p2*wp4.z, a3 = p3*wp4.w;
      float b0 = p0*wn4.x, b1 = p1*wn4.y, b2 = p2*wn4.z, b3 = p3*wn4.w;
      lp += (a0+a1)+(a2+a3);
      ln += (b0+b1)+(b2+b3);
      uint2 pu, nu;
      pu.x = pack_bf16(a0, a1); pu.y = pack_bf16(a2, a3);
      nu.x = pack_bf16(b0, b1); nu.y = pack_bf16(b2, b3);
      const int chunk = b >> 1;
      const int quadA = (b & 1)*2 + (quad >> 1);
      const int addr = chunk*1024 + (quadA*16 + c16)*16 + (quad & 1)*8;
      *(uint2*)&Pw[addr]        = pu;
      *(uint2*)&Pw[2048 + addr] = nu;
    }
    // ---- PV bf16 (A=P frag-major, B=V frag-major) ----
    s8frag ap0 = *(const s8frag*)&Pw[lane*16];
    s8frag ap1 = *(const s8frag*)&Pw[1024 + lane*16];
    s8frag an0 = *(const s8frag*)&Pw[2048 + lane*16];
    s8frag an1 = *(const s8frag*)&Pw[3072 + lane*16];
    #pragma unroll
    for (int nb = 0; nb < 4; nb++) {
      op[nb] = __builtin_amdgcn_mfma_f32_16x16x32_bf16(ap0, vf0[nb], op[nb], 0, 0, 0);
      op[nb] = __builtin_amdgcn_mfma_f32_16x16x32_bf16(ap1, vf1[nb], op[nb], 0, 0, 0);
      on[nb] = __builtin_amdgcn_mfma_f32_16x16x32_bf16(an0, vf0[nb], on[nb], 0, 0, 0);
      on[nb] = __builtin_amdgcn_mfma_f32_16x16x32_bf16(an1, vf1[nb], on[nb], 0, 0, 0);
    }
    pb ^= 1;
  }

  // ---- epilogue ----
  lp += __shfl_xor(lp, 16, 64); lp += __shfl_xor(lp, 32, 64);
  ln += __shfl_xor(ln, 16, 64); ln += __shfl_xor(ln, 32, 64);
  if (quad == 0) {
    int iq = q0 + w*16 + c16;
    if (iq < TOK) {
      Lp[((size_t)half*NH + h)*NQROW + iq] = lp;
      Ln[((size_t)half*NH + h)*NQROW + iq] = ln;
    }
  }
  __syncthreads();                    // all waves done with K/V tiles
  float* Sw = (float*)(smem + w*4608);   // [16][72] overlay
  const int q_l = lane >> 2;
  const int db  = (lane & 3) * 16;
  const int iq = q0 + w*16 + q_l;
  #pragma unroll
  for (int nb = 0; nb < 4; nb++)
    #pragma unroll
    for (int r = 0; r < 4; r++)
      Sw[(quad*4+r)*72 + nb*16+c16] = op[nb][r];
  float vp[16];
  #pragma unroll
  for (int i = 0; i < 16; i++) vp[i] = Sw[q_l*72 + db + i];
  #pragma unroll
  for (int nb = 0; nb < 4; nb++)
    #pragma unroll
    for (int r = 0; r < 4; r++)
      Sw[(quad*4+r)*72 + nb*16+c16] = on[nb][r];
  float vn[16];
  #pragma unroll
  for (int i = 0; i < 16; i++) vn[i] = Sw[q_l*72 + db + i];

  if (iq < TOK) {
    unsigned pk[8], nk[8];
    #pragma unroll
    for (int i = 0; i < 8; i++) {
      pk[i] = pack_bf16(vp[2*i], vp[2*i+1]);
      nk[i] = pack_bf16(vn[2*i], vn[2*i+1]);
    }
    size_t off = (size_t)half*NQROW*CH + (size_t)iq*CH + h*HD + db;
    *(uint4*)(POp + off)     = make_uint4(pk[0], pk[1], pk[2], pk[3]);
    *(uint4*)(POp + off + 8) = make_uint4(pk[4], pk[5], pk[6], pk[7]);
    *(uint4*)(POn + off)     = make_uint4(nk[0], nk[1], nk[2], nk[3]);
    *(uint4*)(POn + off + 8) = make_uint4(nk[4], nk[5], nk[6], nk[7]);
  }
}

// ---------------- merge kernel ------------------------------------------------------
__global__ __launch_bounds__(256) void merge_kernel(
    const ushort_t* __restrict__ POp, const ushort_t* __restrict__ POn,
    const float* __restrict__ Lp, const float* __restrict__ Ln,
    const int* __restrict__ cls, ushort_t* __restrict__ AObf)
{
  const int row = blockIdx.x;
  const int c4 = threadIdx.x * 4;
  const int h = c4 >> 6;
  const size_t o0 = (size_t)row*CH + c4;
  const size_t o1 = (size_t)NQROW*CH + o0;
  ushort4 p0 = *(const ushort4*)(POp + o0);
  ushort4 p1 = *(const ushort4*)(POp + o1);
  ushort4 n0 = *(const ushort4*)(POn + o0);
  ushort4 n1 = *(const ushort4*)(POn + o1);
  const float lpt = Lp[(size_t)h*NQROW + row] + Lp[(size_t)(NH+h)*NQROW + row];
  const float lnt = Ln[(size_t)h*NQROW + row] + Ln[(size_t)(NH+h)*NQROW + row];
  const float ilp = 1.f / lpt, iln = 1.f / lnt;
  const int cq = cls[row];
  float vp[4], vn[4], o[4];
  vp[0] = (bf2f(p0.x)+bf2f(p1.x))*ilp; vn[0] = (bf2f(n0.x)+bf2f(n1.x))*iln;
  vp[1] = (bf2f(p0.y)+bf2f(p1.y))*ilp; vn[1] = (bf2f(n0.y)+bf2f(n1.y))*iln;
  vp[2] = (bf2f(p0.z)+bf2f(p1.z))*ilp; vn[2] = (bf2f(n0.z)+bf2f(n1.z))*iln;
  vp[3] = (bf2f(p0.w)+bf2f(p1.w))*ilp; vn[3] = (bf2f(n0.w)+bf2f(n1.w))*iln;
  if (row < NREG) {
    #pragma unroll
    for (int i = 0; i < 4; i++) o[i] = 0.5f*(vp[i]+vn[i]);
  } else if (cq == 1) {
    #pragma unroll
    for (int i = 0; i < 4; i++) o[i] = vp[i];
  } else {
    #pragma unroll
    for (int i = 0; i < 4; i++) o[i] = vn[i];
  }
  uint2 pk;
  pk.x = pack_bf16(o[0], o[1]);
  pk.y = pack_bf16(o[2], o[3]);
  *(uint2*)(AObf + (size_t)row*CH + c4) = pk;
}

// ---------------- Proj GEMM: 128x128 tile, LDS-staged, dbuf -------------------------
__global__ __launch_bounds__(256) void gemm_proj_mfma(
    const ushort_t* __restrict__ A, const ushort_t* __restrict__ WT,
    const float* __restrict__ bp, float* __restrict__ out)
{
  __shared__ ushort_t LA[2][4096];
  __shared__ ushort_t LB[2][4096];
  const int tid = threadIdx.x;
  const int w = tid >> 6, lane = tid & 63;
  const int quad = lane >> 4, c16 = lane & 15;
  const int wm = w >> 1, wn = w & 1;
  const int nt = blockIdx.x, mt = blockIdx.y;
  const int n0 = nt * 128, m0 = mt * 128;

  const int srow = tid >> 2;
  const int g = (tid & 3) ^ ((tid >> 3) & 3);
  const size_t aoff = (size_t)(m0 + srow)*CH + g*8;
  const size_t boff = (size_t)(n0 + srow)*CH + g*8;
  const int lbase = (tid & 192) * 8;

  f4frag acc[4][4];
  #pragma unroll
  for (int mi = 0; mi < 4; mi++)
    #pragma unroll
    for (int nb = 0; nb < 4; nb++) acc[mi][nb] = (f4frag){0.f,0.f,0.f,0.f};

  const int soff = (quad ^ ((c16 >> 1) & 3)) * 8;
  int aro[4], bro[4];
  #pragma unroll
  for (int i = 0; i < 4; i++) {
    aro[i] = (wm*64 + i*16 + c16)*32 + soff;
    bro[i] = (wn*64 + i*16 + c16)*32 + soff;
  }

#define PROJ_STAGE(KT, BUF) {                                                  \
    const int _k = (KT)*32;                                                    \
    cp16(A  + aoff + _k,                 &LA[BUF][lbase]);                     \
    cp16(A  + aoff + _k + (size_t)64*CH, &LA[BUF][2048 + lbase]);              \
    cp16(WT + boff + _k,                 &LB[BUF][lbase]);                     \
    cp16(WT + boff + _k + (size_t)64*CH, &LB[BUF][2048 + lbase]);              \
    }

  PROJ_STAGE(0, 0);
  for (int kt = 0; kt < 32; kt++) {
    const int buf = kt & 1;
    __syncthreads();
    if (kt < 31) { PROJ_STAGE(kt+1, buf^1); }
    s8frag a[4], b[4];
    #pragma unroll
    for (int i = 0; i < 4; i++) a[i] = *(const s8frag*)&LA[buf][aro[i]];
    #pragma unroll
    for (int i = 0; i < 4; i++) b[i] = *(const s8frag*)&LB[buf][bro[i]];
    #pragma unroll
    for (int mi = 0; mi < 4; mi++)
      #pragma unroll
      for (int nb = 0; nb < 4; nb++)
        acc[mi][nb] = __builtin_amdgcn_mfma_f32_16x16x32_bf16(a[mi], b[nb], acc[mi][nb], 0, 0, 0);
  }
#undef PROJ_STAGE

  #pragma unroll
  for (int mi = 0; mi < 4; mi++) {
    const int orow = m0 + wm*64 + mi*16 + quad*4;
    #pragma unroll
    for (int nb = 0; nb < 4; nb++) {
      const int col = n0 + wn*64 + nb*16 + c16;
      const float bias = bp[col];
      #pragma unroll
      for (int r = 0; r < 4; r++) {
        int row = orow + r;
        if (row < TOK) out[(size_t)row*CH + col] = acc[mi][nb][r] + bias;
      }
    }
  }
}

extern "C" void kernel_launch(void* const* d_in, const int* in_sizes, int n_in,
                              void* d_out, int out_size, void* d_ws, size_t ws_size,
                              hipStream_t stream) {
  const float* x      = (const float*)d_in[0];
  const float* g_info = (const float*)d_in[1];
  const float* W_qkv  = (const float*)d_in[2];
  const float* W_proj = (const float*)d_in[3];
  const float* b_proj = (const float*)d_in[4];
  float* out = (float*)d_out;

  float* ws = (float*)d_ws;
  float* Qf  = ws;                                   // NH*TOK*HD
  float* SIM = Qf + (size_t)NH*TOK*HD;               // NTOK
  float* WP  = SIM + NTOK;                           // NPAD2
  float* WN  = WP + NPAD2;                           // NPAD2
  int*   CLS = (int*)(WN + NPAD2);                   // 2312
  float* LpB = (float*)(CLS + 2312);                 // 2*NH*NQROW
  float* LnB = LpB + (size_t)2*NH*NQROW;             // 2*NH*NQROW
  ushort_t* Xhi    = (ushort_t*)(LnB + (size_t)2*NH*NQROW);
  ushort_t* Xlo    = Xhi    + (size_t)NPADQ*CH;
  ushort_t* WqkvT  = Xlo    + (size_t)NPADQ*CH;      // 3072*1024
  ushort_t* WqkvLo = WqkvT  + (size_t)3*CH*CH;       // 1024*1024
  ushort_t* WprojT = WqkvLo + (size_t)CH*CH;         // 1024*1024
  ushort_t* AObf   = WprojT + (size_t)CH*CH;         // NPADQ*CH
  ushort_t* POp    = AObf   + (size_t)NPADQ*CH;      // 2*NQROW*CH
  ushort_t* POn    = POp    + (size_t)2*NQROW*CH;    // 2*NQROW*CH
  uchar_t*  Q8     = (uchar_t*)(POn + (size_t)2*NQROW*CH);  // NH*NPADQ*64
  uchar_t*  K8     = Q8 + (size_t)NH*NPADQ*64;              // NH*NKT*4096 B
  ushort_t* Vbf    = (ushort_t*)(K8 + (size_t)NH*NKT*4096); // NH*NKT*4096 ushorts

  // zero fp8 K and bf16 V tile buffers (pad rows/tiles must be 0) - adjacent
  hipMemsetAsync(K8, 0, (size_t)NH*NKT*4096 + (size_t)NH*NKT*8192, stream);

  split_x_kernel<<<dim3(NPADQ), 256, 0, stream>>>(x, Xhi, Xlo);
  pack_w_kernel<<<dim3(48, 16), 256, 0, stream>>>(W_qkv, 3*CH, WqkvT, WqkvLo, CH);
  pack_w_kernel<<<dim3(16, 16), 256, 0, stream>>>(W_proj, CH, WprojT, nullptr, 0);
  gemm_qkv_mfma<<<dim3(24, 19), 256, 0, stream>>>(Xhi, Xlo, WqkvT, WqkvLo,
                                                  Qf, Q8, K8, Vbf);
  sim_kernel<<<dim3(576), 256, 0, stream>>>(Qf, g_info, SIM);
  mask_kernel<<<dim3(1), 256, 0, stream>>>(SIM, CLS, WP, WN);
  attn_kernel<<<dim3(37, NH, 2), 256, 0, stream>>>(Q8, K8, Vbf, WP, WN,
                                                   POp, POn, LpB, LnB);
  merge_kernel<<<dim3(TOK), 256, 0, stream>>>(POp, POn, LpB, LnB, CLS, AObf);
  gemm_proj_mfma<<<dim3(8, 19), 256, 0, stream>>>(AObf, WprojT, b_proj, out);
}

// Round 11
// 257.085 us; speedup vs baseline: 2.0158x; 1.0949x over previous
//
#include <hip/hip_runtime.h>
#include <math.h>

#define TOK 2309
#define CH 1024
#define NH 16
#define HD 64
#define NREG 5
#define NTOK (TOK - NREG)    // 2304
#define NPADQ 2432           // 19*128 (query/M padding)
#define NPAD2 2560           // 40*64 (key padding) -> 40 key tiles
#define NKT 40
#define HTILES 20            // K-tiles per half (attention split-K)
#define NQROW 2368           // 37*64 rows in attention output partials
#define QSCL 0.1803368801f   // 0.125 * log2(e)

typedef unsigned short ushort_t;
typedef unsigned char uchar_t;
typedef __attribute__((ext_vector_type(8))) short s8frag;
typedef __attribute__((ext_vector_type(4))) float f4frag;
typedef __attribute__((ext_vector_type(2))) long ll2;

__device__ __forceinline__ float wredsum(float v){
  #pragma unroll
  for (int o = 32; o > 0; o >>= 1) v += __shfl_xor(v, o, 64);
  return v;
}

__device__ __forceinline__ unsigned short f2bf(float x){
  union { float f; unsigned u; } v; v.f = x;
  unsigned r = v.u + 0x7FFF + ((v.u >> 16) & 1);
  return (unsigned short)(r >> 16);
}
__device__ __forceinline__ float bf2f(unsigned short u){
  union { unsigned u32; float f; } v; v.u32 = ((unsigned)u) << 16;
  return v.f;
}
__device__ __forceinline__ unsigned pack_bf16(float lo, float hi){
  union { float f; unsigned u; } a, b;
  a.f = lo; b.f = hi;
  return __builtin_amdgcn_perm(b.u + 0x8000u, a.u + 0x8000u, 0x07060302u);
}
__device__ __forceinline__ uchar_t f2fp8(float x){
  return (uchar_t)(__builtin_amdgcn_cvt_pk_fp8_f32(x, x, 0, false) & 0xff);
}
// async global->LDS 16B/lane; lds ptr must be wave-uniform (HW adds lane*16)
__device__ __forceinline__ void cp16(const void* g, void* l){
  __builtin_amdgcn_global_load_lds(
      (const __attribute__((address_space(1))) unsigned int*)g,
      (__attribute__((address_space(3))) unsigned int*)l, 16, 0, 0);
}

// ---------------- split X into hi/lo bf16 (rows padded to NPADQ with zeros) --------
__global__ __launch_bounds__(256) void split_x_kernel(
    const float* __restrict__ X, ushort_t* __restrict__ Xhi, ushort_t* __restrict__ Xlo)
{
  int row = blockIdx.x;
  int c4 = threadIdx.x * 4;
  ushort4 h4 = {0,0,0,0}, l4 = {0,0,0,0};
  if (row < TOK) {
    float4 v = *(const float4*)&X[(size_t)row*CH + c4];
    float vv[4] = {v.x, v.y, v.z, v.w};
    ushort_t hs[4], ls[4];
    #pragma unroll
    for (int i = 0; i < 4; i++) {
      hs[i] = f2bf(vv[i]);
      ls[i] = f2bf(vv[i] - bf2f(hs[i]));
    }
    h4.x=hs[0]; h4.y=hs[1]; h4.z=hs[2]; h4.w=hs[3];
    l4.x=ls[0]; l4.y=ls[1]; l4.z=ls[2]; l4.w=ls[3];
  }
  *(ushort4*)&Xhi[(size_t)row*CH + c4] = h4;
  *(ushort4*)&Xlo[(size_t)row*CH + c4] = l4;
}

// ---------------- transpose+split W: W(1024 x N) -> WT(N x 1024) bf16 (+lo) --------
__global__ __launch_bounds__(256) void pack_w_kernel(
    const float* __restrict__ W, const int N,
    ushort_t* __restrict__ WT, ushort_t* __restrict__ WloT, const int loN)
{
  __shared__ float T[64][68];
  const int tid = threadIdx.x;
  const int n0 = blockIdx.x * 64;
  const int k0 = blockIdx.y * 64;
  const int lr = tid >> 4;
  const int lc = (tid & 15) * 4;
  #pragma unroll
  for (int s = 0; s < 4; s++) {
    float4 v = *(const float4*)&W[(size_t)(k0 + lr + s*16) * N + n0 + lc];
    *(float4*)&T[lr + s*16][lc] = v;
  }
  __syncthreads();
  const int nl = tid >> 2;
  const int kc = (tid & 3) * 16;
  const bool dolo = (WloT != nullptr) && (n0 < loN);
  ushort_t* dh = WT + (size_t)(n0 + nl) * CH + k0 + kc;
  ushort_t* dl = WloT + (size_t)(n0 + nl) * CH + k0 + kc;
  #pragma unroll
  for (int g = 0; g < 4; g++) {
    float a = T[kc+g*4+0][nl], b = T[kc+g*4+1][nl];
    float c = T[kc+g*4+2][nl], d = T[kc+g*4+3][nl];
    ushort4 oh;
    oh.x=f2bf(a); oh.y=f2bf(b); oh.z=f2bf(c); oh.w=f2bf(d);
    *(ushort4*)&dh[g*4] = oh;
    if (dolo) {
      ushort4 ol;
      ol.x=f2bf(a-bf2f(oh.x)); ol.y=f2bf(b-bf2f(oh.y));
      ol.z=f2bf(c-bf2f(oh.z)); ol.w=f2bf(d-bf2f(oh.w));
      *(ushort4*)&dl[g*4] = ol;
    }
  }
}

// ---------------- QKV GEMM: 128x128 tile, LDS-staged dbuf ---------------------------
// Q -> Qf fp32 + Q8 fp8; K -> K8 fp8 frag-major; V -> Vbf bf16 in PV-A-operand
// layout with k-permutation J(c,quadA,i) = c*32 + 16*(i>=4) + quadA*4 + (i&3):
//   Vbf[h][tile][dblk][c][lane=quadA*16+c16A][i] = V[tile*64 + J][d = dblk*16+c16A]
__global__ __launch_bounds__(256) void gemm_qkv_mfma(
    const ushort_t* __restrict__ Xhi, const ushort_t* __restrict__ Xlo,
    const ushort_t* __restrict__ WhiT, const ushort_t* __restrict__ WloT,
    float* __restrict__ Qf, uchar_t* __restrict__ Q8,
    uchar_t* __restrict__ K8, ushort_t* __restrict__ Vbf)
{
  __shared__ ushort_t LA[2][2][4096];
  __shared__ ushort_t LB[2][2][4096];
  const int tid = threadIdx.x;
  const int w = tid >> 6, lane = tid & 63;
  const int quad = lane >> 4, c16 = lane & 15;
  const int wm = w >> 1, wn = w & 1;
  const int nt = blockIdx.x, mt = blockIdx.y;
  const int n0 = nt * 128, m0 = mt * 128;
  const bool isQ = (nt < 8);

  const int srow = tid >> 2;
  const int g = (tid & 3) ^ ((tid >> 3) & 3);
  const size_t aoff = (size_t)(m0 + srow)*CH + g*8;
  const size_t boff = (size_t)(n0 + srow)*CH + g*8;
  const int lbase = (tid & 192) * 8;

  f4frag acc[4][4];
  #pragma unroll
  for (int mi = 0; mi < 4; mi++)
    #pragma unroll
    for (int nb = 0; nb < 4; nb++) acc[mi][nb] = (f4frag){0.f,0.f,0.f,0.f};

  const int soff = (quad ^ ((c16 >> 1) & 3)) * 8;
  int aro[4], bro[4];
  #pragma unroll
  for (int i = 0; i < 4; i++) {
    aro[i] = (wm*64 + i*16 + c16)*32 + soff;
    bro[i] = (wn*64 + i*16 + c16)*32 + soff;
  }

#define QKV_STAGE(KT, BUF) {                                                   \
    const int _k = (KT)*32;                                                    \
    cp16(Xhi  + aoff + _k,                 &LA[BUF][0][lbase]);                \
    cp16(Xhi  + aoff + _k + (size_t)64*CH, &LA[BUF][0][2048 + lbase]);         \
    cp16(WhiT + boff + _k,                 &LB[BUF][0][lbase]);                \
    cp16(WhiT + boff + _k + (size_t)64*CH, &LB[BUF][0][2048 + lbase]);         \
    if (isQ) {                                                                 \
      cp16(Xlo  + aoff + _k,                 &LA[BUF][1][lbase]);              \
      cp16(Xlo  + aoff + _k + (size_t)64*CH, &LA[BUF][1][2048 + lbase]);       \
      cp16(WloT + boff + _k,                 &LB[BUF][1][lbase]);              \
      cp16(WloT + boff + _k + (size_t)64*CH, &LB[BUF][1][2048 + lbase]);       \
    } }

  QKV_STAGE(0, 0);
  for (int kt = 0; kt < 32; kt++) {
    const int buf = kt & 1;
    __syncthreads();
    if (kt < 31) { QKV_STAGE(kt+1, buf^1); }
    s8frag a[4], b[4];
    #pragma unroll
    for (int i = 0; i < 4; i++) a[i] = *(const s8frag*)&LA[buf][0][aro[i]];
    #pragma unroll
    for (int i = 0; i < 4; i++) b[i] = *(const s8frag*)&LB[buf][0][bro[i]];
    #pragma unroll
    for (int mi = 0; mi < 4; mi++)
      #pragma unroll
      for (int nb = 0; nb < 4; nb++)
        acc[mi][nb] = __builtin_amdgcn_mfma_f32_16x16x32_bf16(a[mi], b[nb], acc[mi][nb], 0, 0, 0);
    if (isQ) {
      s8frag al[4], bl[4];
      #pragma unroll
      for (int i = 0; i < 4; i++) al[i] = *(const s8frag*)&LA[buf][1][aro[i]];
      #pragma unroll
      for (int i = 0; i < 4; i++) bl[i] = *(const s8frag*)&LB[buf][1][bro[i]];
      #pragma unroll
      for (int mi = 0; mi < 4; mi++)
        #pragma unroll
        for (int nb = 0; nb < 4; nb++) {
          acc[mi][nb] = __builtin_amdgcn_mfma_f32_16x16x32_bf16(a[mi],  bl[nb], acc[mi][nb], 0, 0, 0);
          acc[mi][nb] = __builtin_amdgcn_mfma_f32_16x16x32_bf16(al[mi], b[nb],  acc[mi][nb], 0, 0, 0);
        }
    }
  }
#undef QKV_STAGE

  const int three = (nt >= 16) ? 2 : (nt >= 8) ? 1 : 0;
  #pragma unroll
  for (int mi = 0; mi < 4; mi++) {
    const int orow = m0 + wm*64 + mi*16 + quad*4;
    if (three == 0) {
      #pragma unroll
      for (int nb = 0; nb < 4; nb++) {
        const int col = n0 + wn*64 + nb*16 + c16;
        const int h = (col >> 6) & 15, d = col & 63;
        float* qf = Qf + (size_t)h*TOK*HD;
        uchar_t* q8 = Q8 + (size_t)h*NPADQ*64;
        #pragma unroll
        for (int r = 0; r < 4; r++) {
          int row = orow + r;
          float v = (row < TOK) ? acc[mi][nb][r] : 0.f;
          if (row < TOK) qf[(size_t)row*HD + d] = v;
          q8[(size_t)row*64 + d] = f2fp8(v);
        }
      }
    } else if (three == 1) {
      #pragma unroll
      for (int nb = 0; nb < 4; nb++) {
        const int col = n0 + wn*64 + nb*16 + c16;
        const int h = (col >> 6) & 15;
        const int quadK = ((nb & 1) * 2) + (c16 >> 3);
        const int byteoff = (nb >> 1) * 8 + (c16 & 7);
        uchar_t* base = K8 + (size_t)h*NKT*4096;
        #pragma unroll
        for (int r = 0; r < 4; r++) {
          int row = orow + r;
          float v = (row < TOK) ? acc[mi][nb][r] : 0.f;
          int tile = row >> 6, b = (row >> 4) & 3, c16K = row & 15;
          base[(size_t)tile*4096 + b*1024 + (quadK*16 + c16K)*16 + byteoff] = f2fp8(v);
        }
      }
    } else {
      const int tile  = orow >> 6;
      const int jj    = orow & 63;
      const int c     = jj >> 5;
      const int t16   = (jj >> 4) & 1;
      const int quadA = (jj >> 2) & 3;
      #pragma unroll
      for (int nb = 0; nb < 4; nb++) {
        const int col = n0 + wn*64 + nb*16 + c16;
        const int h = (col >> 6) & 15, d = col & 63;
        const int dblk = d >> 4, c16A = d & 15;
        ushort_t* base = Vbf + (size_t)h*NKT*4096;   // 4096 ushorts per tile
        ushort4 o;
        o.x = f2bf((orow+0 < TOK) ? acc[mi][nb][0] : 0.f);
        o.y = f2bf((orow+1 < TOK) ? acc[mi][nb][1] : 0.f);
        o.z = f2bf((orow+2 < TOK) ? acc[mi][nb][2] : 0.f);
        o.w = f2bf((orow+3 < TOK) ? acc[mi][nb][3] : 0.f);
        *(ushort4*)&base[(size_t)tile*4096 + dblk*1024 + c*512
                         + (quadA*16 + c16A)*8 + 4*t16] = o;
      }
    }
  }
}

// ---------------- sim kernel (fp32 Q) ----------------------------------------------
__global__ __launch_bounds__(256) void sim_kernel(
    const float* __restrict__ Q, const float* __restrict__ G, float* __restrict__ sim)
{
  const int tid = threadIdx.x;
  const int w = tid >> 6, lane = tid & 63;
  float qgn[NH];
  #pragma unroll
  for (int h = 0; h < NH; h++) {
    float g = G[h*HD + lane];
    float n2 = wredsum(g*g);
    qgn[h] = g / sqrtf(n2);
  }
  int it = blockIdx.x * 4 + w;
  if (it >= NTOK) return;
  int i = NREG + it;
  float acc = 0.f;
  #pragma unroll
  for (int h = 0; h < NH; h++) {
    float qv = Q[((size_t)h*TOK + i)*HD + lane];
    float dot = wredsum(qv * qgn[h]);
    float n2  = wredsum(qv * qv);
    acc += dot / sqrtf(n2);
  }
  if (lane == 0) sim[it] = acc * (1.0f/16.0f);
}

// ---------------- mask kernel ------------------------------------------------------
__global__ __launch_bounds__(256) void mask_kernel(
    const float* __restrict__ sim, int* __restrict__ cls,
    float* __restrict__ WP, float* __restrict__ WN)
{
  __shared__ float smn[256], smx[256];
  const int tid = threadIdx.x;
  float mn = 1e30f, mx = -1e30f;
  for (int i = tid; i < NTOK; i += 256) { float s = sim[i]; mn = fminf(mn, s); mx = fmaxf(mx, s); }
  smn[tid] = mn; smx[tid] = mx;
  __syncthreads();
  for (int off = 128; off > 0; off >>= 1) {
    if (tid < off) { smn[tid] = fminf(smn[tid], smn[tid+off]); smx[tid] = fmaxf(smx[tid], smx[tid+off]); }
    __syncthreads();
  }
  mn = smn[0]; mx = smx[0];
  float inv = 1.0f / (mx - mn);
  for (int j = tid; j < NPAD2; j += 256) {
    float wp = 0.f, wn = 0.f; int c = 0;
    if (j < NREG) { wp = 1.f; wn = 1.f; c = 2; }
    else if (j < TOK) {
      bool pos = ((sim[j-NREG] - mn) * inv) > 0.9f;
      c = pos ? 1 : 0;
      wp = pos ? 1.f : 0.f;
      wn = pos ? 0.f : 1.f;
    }
    WP[j] = wp; WN[j] = wn;
    if (j < TOK) cls[j] = c;
  }
}

// ---------------- flash attention: fp8 QK, register-P bf16 PV (O^T form) ------------
// LDS: K dbuf 8 KB + V dbuf 16 KB = 24 KB. No P round-trip, no epilogue transpose.
__global__ __launch_bounds__(256) void attn_kernel(
    const uchar_t* __restrict__ Q8, const uchar_t* __restrict__ K8,
    const ushort_t* __restrict__ Vbf,
    const float* __restrict__ WP, const float* __restrict__ WN,
    ushort_t* __restrict__ POp, ushort_t* __restrict__ POn,
    float* __restrict__ Lp, float* __restrict__ Ln)
{
  __shared__ __align__(16) uchar_t smem[24576];
  uchar_t* Kst = smem;                 // [2][4096]
  uchar_t* Vst = smem + 8192;          // [2][8192]
  const int tid = threadIdx.x;
  const int w = tid >> 6, lane = tid & 63;
  const int quad = lane >> 4, c16 = lane & 15;
  const int h = blockIdx.y;
  const int half = blockIdx.z;
  const int q0 = blockIdx.x * 64;

  const uchar_t* Qh = Q8 + (size_t)h * NPADQ * 64;
  const uchar_t* gk = K8 + ((size_t)h*NKT + half*HTILES)*4096 + tid*16;
  const uchar_t* gv = (const uchar_t*)Vbf + ((size_t)h*NKT + half*HTILES)*8192 + tid*16;
  const int lw = w * 1024;   // wave-uniform LDS offset for cp16

  const uchar_t* qp = Qh + (size_t)(q0 + w*16 + c16)*64 + quad*8;
  const long qf0 = *(const long*)(qp);
  const long qf1 = *(const long*)(qp + 32);

  f4frag op[4], on[4];
  #pragma unroll
  for (int nb = 0; nb < 4; nb++) { op[nb] = (f4frag){0.f,0.f,0.f,0.f}; on[nb] = (f4frag){0.f,0.f,0.f,0.f}; }
  float lp = 0.f, ln = 0.f;

  cp16(gk, Kst + lw);
  cp16(gv, Vst + lw);
  cp16(gv + 4096, Vst + 4096 + lw);

  int pb = 0;
  for (int t = 0; t < HTILES; t++) {
    __syncthreads();
    if (t < HTILES-1) {
      cp16(gk + (size_t)(t+1)*4096, Kst + (pb^1)*4096 + lw);
      cp16(gv + (size_t)(t+1)*8192,        Vst + (pb^1)*8192 + lw);
      cp16(gv + (size_t)(t+1)*8192 + 4096, Vst + (pb^1)*8192 + 4096 + lw);
    }
    const int j0 = half*(HTILES*64) + t*64;
    // ---- QK fp8 (A=K frag-major, B=Q): st[b] C-layout: lane holds (q=c16,
    //      j = b*16 + quad*4 + r) ----
    f4frag st[4];
    #pragma unroll
    for (int b = 0; b < 4; b++) {
      ll2 kv = *(const ll2*)&Kst[pb*4096 + b*1024 + lane*16];
      f4frag z = (f4frag){0.f,0.f,0.f,0.f};
      z     = __builtin_amdgcn_mfma_f32_16x16x32_fp8_fp8(kv.x, qf0, z, 0, 0, 0);
      st[b] = __builtin_amdgcn_mfma_f32_16x16x32_fp8_fp8(kv.y, qf1, z, 0, 0, 0);
    }
    // ---- p = exp2(s*QSCL); weight; pack into register B-frags (P^T) ----
    unsigned pu[4][2], nu[4][2];
    #pragma unroll
    for (int b = 0; b < 4; b++) {
      float4 wp4 = *(const float4*)&WP[j0 + b*16 + quad*4];
      float4 wn4 = *(const float4*)&WN[j0 + b*16 + quad*4];
      float p0 = __builtin_amdgcn_exp2f(st[b][0] * QSCL);
      float p1 = __builtin_amdgcn_exp2f(st[b][1] * QSCL);
      float p2 = __builtin_amdgcn_exp2f(st[b][2] * QSCL);
      float p3 = __builtin_amdgcn_exp2f(st[b][3] * QSCL);
      float a0 = p0*wp4.x, a1 = p1*wp4.y, a2 = p2*wp4.z, a3 = p3*wp4.w;
      float b0 = p0*wn4.x, b1 = p1*wn4.y, b2 = p2*wn4.z, b3 = p3*wn4.w;
      lp += (a0+a1)+(a2+a3);
      ln += (b0+b1)+(b2+b3);
      pu[b][0] = pack_bf16(a0, a1); pu[b][1] = pack_bf16(a2, a3);
      nu[b][0] = pack_bf16(b0, b1); nu[b][1] = pack_bf16(b2, b3);
    }
    union Frag { unsigned u[4]; s8frag v; };
    Frag fp0, fp1, fn0, fn1;
    fp0.u[0]=pu[0][0]; fp0.u[1]=pu[0][1]; fp0.u[2]=pu[1][0]; fp0.u[3]=pu[1][1];
    fp1.u[0]=pu[2][0]; fp1.u[1]=pu[2][1]; fp1.u[2]=pu[3][0]; fp1.u[3]=pu[3][1];
    fn0.u[0]=nu[0][0]; fn0.u[1]=nu[0][1]; fn0.u[2]=nu[1][0]; fn0.u[3]=nu[1][1];
    fn1.u[0]=nu[2][0]; fn1.u[1]=nu[2][1]; fn1.u[2]=nu[3][0]; fn1.u[3]=nu[3][1];
    // ---- PV: O^T[d][q] += V^T-frag (LDS, k-permuted) x P^T-frag (regs) ----
    #pragma unroll
    for (int nb = 0; nb < 4; nb++) {
      s8frag va = *(const s8frag*)&Vst[pb*8192 + nb*2048 + lane*16];
      s8frag vb = *(const s8frag*)&Vst[pb*8192 + nb*2048 + 1024 + lane*16];
      op[nb] = __builtin_amdgcn_mfma_f32_16x16x32_bf16(va, fp0.v, op[nb], 0, 0, 0);
      op[nb] = __builtin_amdgcn_mfma_f32_16x16x32_bf16(vb, fp1.v, op[nb], 0, 0, 0);
      on[nb] = __builtin_amdgcn_mfma_f32_16x16x32_bf16(va, fn0.v, on[nb], 0, 0, 0);
      on[nb] = __builtin_amdgcn_mfma_f32_16x16x32_bf16(vb, fn1.v, on[nb], 0, 0, 0);
    }
    pb ^= 1;
  }

  // ---- epilogue: O^T C-layout = lane q=c16 holds d = nb*16 + quad*4 + r ----
  lp += __shfl_xor(lp, 16, 64); lp += __shfl_xor(lp, 32, 64);
  ln += __shfl_xor(ln, 16, 64); ln += __shfl_xor(ln, 32, 64);
  const int iq = q0 + w*16 + c16;
  if (quad == 0 && iq < TOK) {
    Lp[((size_t)half*NH + h)*NQROW + iq] = lp;
    Ln[((size_t)half*NH + h)*NQROW + iq] = ln;
  }
  if (iq < TOK) {
    const size_t base = (size_t)half*NQROW*CH + (size_t)iq*CH + h*HD;
    #pragma unroll
    for (int nb = 0; nb < 4; nb++) {
      uint2 po, no;
      po.x = pack_bf16(op[nb][0], op[nb][1]);
      po.y = pack_bf16(op[nb][2], op[nb][3]);
      no.x = pack_bf16(on[nb][0], on[nb][1]);
      no.y = pack_bf16(on[nb][2], on[nb][3]);
      *(uint2*)(POp + base + nb*16 + quad*4) = po;
      *(uint2*)(POn + base + nb*16 + quad*4) = no;
    }
  }
}

// ---------------- merge kernel ------------------------------------------------------
__global__ __launch_bounds__(256) void merge_kernel(
    const ushort_t* __restrict__ POp, const ushort_t* __restrict__ POn,
    const float* __restrict__ Lp, const float* __restrict__ Ln,
    const int* __restrict__ cls, ushort_t* __restrict__ AObf)
{
  const int row = blockIdx.x;
  const int c4 = threadIdx.x * 4;
  const int h = c4 >> 6;
  const size_t o0 = (size_t)row*CH + c4;
  const size_t o1 = (size_t)NQROW*CH + o0;
  ushort4 p0 = *(const ushort4*)(POp + o0);
  ushort4 p1 = *(const ushort4*)(POp + o1);
  ushort4 n0 = *(const ushort4*)(POn + o0);
  ushort4 n1 = *(const ushort4*)(POn + o1);
  const float lpt = Lp[(size_t)h*NQROW + row] + Lp[(size_t)(NH+h)*NQROW + row];
  const float lnt = Ln[(size_t)h*NQROW + row] + Ln[(size_t)(NH+h)*NQROW + row];
  const float ilp = 1.f / lpt, iln = 1.f / lnt;
  const int cq = cls[row];
  float vp[4], vn[4], o[4];
  vp[0] = (bf2f(p0.x)+bf2f(p1.x))*ilp; vn[0] = (bf2f(n0.x)+bf2f(n1.x))*iln;
  vp[1] = (bf2f(p0.y)+bf2f(p1.y))*ilp; vn[1] = (bf2f(n0.y)+bf2f(n1.y))*iln;
  vp[2] = (bf2f(p0.z)+bf2f(p1.z))*ilp; vn[2] = (bf2f(n0.z)+bf2f(n1.z))*iln;
  vp[3] = (bf2f(p0.w)+bf2f(p1.w))*ilp; vn[3] = (bf2f(n0.w)+bf2f(n1.w))*iln;
  if (row < NREG) {
    #pragma unroll
    for (int i = 0; i < 4; i++) o[i] = 0.5f*(vp[i]+vn[i]);
  } else if (cq == 1) {
    #pragma unroll
    for (int i = 0; i < 4; i++) o[i] = vp[i];
  } else {
    #pragma unroll
    for (int i = 0; i < 4; i++) o[i] = vn[i];
  }
  uint2 pk;
  pk.x = pack_bf16(o[0], o[1]);
  pk.y = pack_bf16(o[2], o[3]);
  *(uint2*)(AObf + (size_t)row*CH + c4) = pk;
}

// ---------------- Proj GEMM: 128M x 64N tiles (24 KB LDS, 6 blocks/CU) ---------------
__global__ __launch_bounds__(256) void gemm_proj_mfma(
    const ushort_t* __restrict__ A, const ushort_t* __restrict__ WT,
    const float* __restrict__ bp, float* __restrict__ out)
{
  __shared__ ushort_t LA[2][4096];   // 128 rows x 32 k
  __shared__ ushort_t LB[2][2048];   // 64 rows x 32 k
  const int tid = threadIdx.x;
  const int w = tid >> 6, lane = tid & 63;
  const int quad = lane >> 4, c16 = lane & 15;
  const int wm = w >> 1, wn = w & 1;
  const int nt = blockIdx.x, mt = blockIdx.y;
  const int n0 = nt * 64, m0 = mt * 128;

  const int srow = tid >> 2;
  const int g = (tid & 3) ^ ((tid >> 3) & 3);
  const size_t aoff = (size_t)(m0 + srow)*CH + g*8;
  const size_t boff = (size_t)(n0 + srow)*CH + g*8;
  const int lbase = (tid & 192) * 8;

  f4frag acc[4][2];
  #pragma unroll
  for (int mi = 0; mi < 4; mi++)
    #pragma unroll
    for (int nb = 0; nb < 2; nb++) acc[mi][nb] = (f4frag){0.f,0.f,0.f,0.f};

  const int soff = (quad ^ ((c16 >> 1) & 3)) * 8;
  int aro[4], bro[2];
  #pragma unroll
  for (int i = 0; i < 4; i++) aro[i] = (wm*64 + i*16 + c16)*32 + soff;
  #pragma unroll
  for (int i = 0; i < 2; i++) bro[i] = (wn*32 + i*16 + c16)*32 + soff;

#define PROJ_STAGE(KT, BUF) {                                                  \
    const int _k = (KT)*32;                                                    \
    cp16(A  + aoff + _k,                 &LA[BUF][lbase]);                     \
    cp16(A  + aoff + _k + (size_t)64*CH, &LA[BUF][2048 + lbase]);              \
    cp16(WT + boff + _k,                 &LB[BUF][lbase]);                     \
    }

  PROJ_STAGE(0, 0);
  for (int kt = 0; kt < 32; kt++) {
    const int buf = kt & 1;
    __syncthreads();
    if (kt < 31) { PROJ_STAGE(kt+1, buf^1); }
    s8frag a[4], b[2];
    #pragma unroll
    for (int i = 0; i < 4; i++) a[i] = *(const s8frag*)&LA[buf][aro[i]];
    #pragma unroll
    for (int i = 0; i < 2; i++) b[i] = *(const s8frag*)&LB[buf][bro[i]];
    #pragma unroll
    for (int mi = 0; mi < 4; mi++)
      #pragma unroll
      for (int nb = 0; nb < 2; nb++)
        acc[mi][nb] = __builtin_amdgcn_mfma_f32_16x16x32_bf16(a[mi], b[nb], acc[mi][nb], 0, 0, 0);
  }
#undef PROJ_STAGE

  #pragma unroll
  for (int mi = 0; mi < 4; mi++) {
    const int orow = m0 + wm*64 + mi*16 + quad*4;
    #pragma unroll
    for (int nb = 0; nb < 2; nb++) {
      const int col = n0 + wn*32 + nb*16 + c16;
      const float bias = bp[col];
      #pragma unroll
      for (int r = 0; r < 4; r++) {
        int row = orow + r;
        if (row < TOK) out[(size_t)row*CH + col] = acc[mi][nb][r] + bias;
      }
    }
  }
}

extern "C" void kernel_launch(void* const* d_in, const int* in_sizes, int n_in,
                              void* d_out, int out_size, void* d_ws, size_t ws_size,
                              hipStream_t stream) {
  const float* x      = (const float*)d_in[0];
  const float* g_info = (const float*)d_in[1];
  const float* W_qkv  = (const float*)d_in[2];
  const float* W_proj = (const float*)d_in[3];
  const float* b_proj = (const float*)d_in[4];
  float* out = (float*)d_out;

  float* ws = (float*)d_ws;
  float* Qf  = ws;                                   // NH*TOK*HD
  float* SIM = Qf + (size_t)NH*TOK*HD;               // NTOK
  float* WP  = SIM + NTOK;                           // NPAD2
  float* WN  = WP + NPAD2;                           // NPAD2
  int*   CLS = (int*)(WN + NPAD2);                   // 2312
  float* LpB = (float*)(CLS + 2312);                 // 2*NH*NQROW
  float* LnB = LpB + (size_t)2*NH*NQROW;             // 2*NH*NQROW
  ushort_t* Xhi    = (ushort_t*)(LnB + (size_t)2*NH*NQROW);
  ushort_t* Xlo    = Xhi    + (size_t)NPADQ*CH;
  ushort_t* WqkvT  = Xlo    + (size_t)NPADQ*CH;      // 3072*1024
  ushort_t* WqkvLo = WqkvT  + (size_t)3*CH*CH;       // 1024*1024
  ushort_t* WprojT = WqkvLo + (size_t)CH*CH;         // 1024*1024
  ushort_t* AObf   = WprojT + (size_t)CH*CH;         // NPADQ*CH
  ushort_t* POp    = AObf   + (size_t)NPADQ*CH;      // 2*NQROW*CH
  ushort_t* POn    = POp    + (size_t)2*NQROW*CH;    // 2*NQROW*CH
  uchar_t*  Q8     = (uchar_t*)(POn + (size_t)2*NQROW*CH);  // NH*NPADQ*64
  uchar_t*  K8     = Q8 + (size_t)NH*NPADQ*64;              // NH*NKT*4096 B
  ushort_t* Vbf    = (ushort_t*)(K8 + (size_t)NH*NKT*4096); // NH*NKT*4096 ushorts

  // zero fp8 K and bf16 V tile buffers (pad rows/tiles must be 0) - adjacent
  hipMemsetAsync(K8, 0, (size_t)NH*NKT*4096 + (size_t)NH*NKT*8192, stream);

  split_x_kernel<<<dim3(NPADQ), 256, 0, stream>>>(x, Xhi, Xlo);
  pack_w_kernel<<<dim3(48, 16), 256, 0, stream>>>(W_qkv, 3*CH, WqkvT, WqkvLo, CH);
  pack_w_kernel<<<dim3(16, 16), 256, 0, stream>>>(W_proj, CH, WprojT, nullptr, 0);
  gemm_qkv_mfma<<<dim3(24, 19), 256, 0, stream>>>(Xhi, Xlo, WqkvT, WqkvLo,
                                                  Qf, Q8, K8, Vbf);
  sim_kernel<<<dim3(576), 256, 0, stream>>>(Qf, g_info, SIM);
  mask_kernel<<<dim3(1), 256, 0, stream>>>(SIM, CLS, WP, WN);
  attn_kernel<<<dim3(37, NH, 2), 256, 0, stream>>>(Q8, K8, Vbf, WP, WN,
                                                   POp, POn, LpB, LnB);
  merge_kernel<<<dim3(TOK), 256, 0, stream>>>(POp, POn, LpB, LnB, CLS, AObf);
  gemm_proj_mfma<<<dim3(16, 19), 256, 0, stream>>>(AObf, WprojT, b_proj, out);
}